// Round 10
// baseline (440.792 us; speedup 1.0000x reference)
//
#include <hip/hip_runtime.h>

#define N_CLASS 10
#define HIDDEN 128
#define BN_EPS 1e-5f

typedef short short8 __attribute__((ext_vector_type(8)));   // 8 bf16 in 4 VGPRs
typedef float floatx4 __attribute__((ext_vector_type(4)));

__device__ __forceinline__ float bf2f(unsigned short u) {
    unsigned int x = ((unsigned int)u) << 16;
    float f; __builtin_memcpy(&f, &x, 4); return f;
}
__device__ __forceinline__ unsigned short f2bf(float f) {
    unsigned int x; __builtin_memcpy(&x, &f, 4);
    x += 0x7FFFu + ((x >> 16) & 1u);          // round-to-nearest-even
    return (unsigned short)(x >> 16);
}
// exact bf16 unpack of a packed uint, 1 VALU op each
__device__ __forceinline__ float lo_f(unsigned int u) {
    unsigned int x = u << 16; float f; __builtin_memcpy(&f, &x, 4); return f;
}
__device__ __forceinline__ float hi_f(unsigned int u) {
    unsigned int x = u & 0xffff0000u; float f; __builtin_memcpy(&f, &x, 4); return f;
}

// ================= bucketed CSR build (no per-edge global atomics) ==========
// bucket = dst >> 8  (256 dsts per bucket; NBK = ceil(N/256) = 391 <= 512)
// pairs entry packed: src (low 24 bits, src < 2^17) | dst&255 (high 8 bits)

__global__ __launch_bounds__(512) void bhist_k(const int* __restrict__ ei,
                                               int* __restrict__ bhist, int E) {
    __shared__ int h[512];
    int tid = threadIdx.x;
    h[tid] = 0;
    __syncthreads();
    for (int e = blockIdx.x * 512 + tid; e < E; e += gridDim.x * 512)
        atomicAdd(&h[((unsigned)ei[E + e]) >> 8], 1);
    __syncthreads();
    if (h[tid]) atomicAdd(&bhist[tid], h[tid]);
}

__global__ __launch_bounds__(512) void bscan_k(const int* __restrict__ bhist,
                                               int* __restrict__ bstart,
                                               int* __restrict__ bcur, int NBK) {
    __shared__ int sm[512];
    int t = threadIdx.x;
    sm[t] = (t < NBK) ? bhist[t] : 0;
    __syncthreads();
    for (int off = 1; off < 512; off <<= 1) {
        int u = (t >= off) ? sm[t - off] : 0;
        __syncthreads();
        sm[t] += u;
        __syncthreads();
    }
    int excl = (t == 0) ? 0 : sm[t - 1];
    if (t <= NBK) bstart[t] = excl;
    if (t < NBK)  bcur[t]   = excl;
}

__global__ __launch_bounds__(512) void bscatter_k(const int* __restrict__ ei,
                                                  int* __restrict__ bcur,
                                                  unsigned int* __restrict__ pairs, int E) {
    __shared__ int h[512], base[512], cur[512];
    int tid = threadIdx.x;
    h[tid] = 0; cur[tid] = 0;
    __syncthreads();
    int chunk = (E + gridDim.x - 1) / gridDim.x;
    int e0 = blockIdx.x * chunk;
    int e1 = min(e0 + chunk, E);
    for (int e = e0 + tid; e < e1; e += 512)
        atomicAdd(&h[((unsigned)ei[E + e]) >> 8], 1);
    __syncthreads();
    base[tid] = h[tid] ? atomicAdd(&bcur[tid], h[tid]) : 0;
    __syncthreads();
    for (int e = e0 + tid; e < e1; e += 512) {
        unsigned int s = (unsigned int)ei[e];
        unsigned int d = (unsigned int)ei[E + e];
        int bk = d >> 8;
        int r = atomicAdd(&cur[bk], 1);      // LDS
        pairs[base[bk] + r] = s | ((d & 255u) << 24);
    }
}

__global__ __launch_bounds__(512) void bcsr_k(const unsigned int* __restrict__ pairs,
                                              const int* __restrict__ bstart,
                                              int* __restrict__ row_ptr,
                                              int* __restrict__ cnt,
                                              int* __restrict__ col, int N) {
    __shared__ int h[256], sc[256], cur[256];
    int tid = threadIdx.x;
    if (tid < 256) { h[tid] = 0; cur[tid] = 0; }
    __syncthreads();
    int b = blockIdx.x, lo = b << 8;
    int s = bstart[b], e = bstart[b + 1];
    for (int i = s + tid; i < e; i += 512)
        atomicAdd(&h[pairs[i] >> 24], 1);    // LDS
    __syncthreads();
    if (tid < 256) sc[tid] = h[tid];
    __syncthreads();
    for (int off = 1; off < 256; off <<= 1) {
        int u = (tid < 256 && tid >= off) ? sc[tid - off] : 0;
        __syncthreads();
        if (tid < 256) sc[tid] += u;
        __syncthreads();
    }
    if (tid < 256) {
        int d = lo + tid;
        if (d < N) { cnt[d] = h[tid]; row_ptr[d] = s + sc[tid] - h[tid]; }
        sc[tid] -= h[tid];                   // exclusive, for the fill below
    }
    __syncthreads();
    for (int i = s + tid; i < e; i += 512) {
        unsigned int p = pairs[i];
        int d = p >> 24;
        int r = atomicAdd(&cur[d], 1);       // LDS
        col[s + sc[d] + r] = (int)(p & 0xFFFFFFu);
    }
}

// === prep: Wt bf16 transpose x3 + zero stats/bhist + pad x -> xp bf16 =======
__global__ void prep_k(const float* __restrict__ W0, const float* __restrict__ W1,
                       const float* __restrict__ W2,
                       unsigned short* __restrict__ T0, unsigned short* __restrict__ T1,
                       unsigned short* __restrict__ T2,
                       float* __restrict__ stats, int* __restrict__ bhist,
                       const float* __restrict__ x, unsigned short* __restrict__ xp,
                       int N) {
    int y = blockIdx.y;
    int i = blockIdx.x * 256 + threadIdx.x;
    if (y < 3) {
        const float* W = (y == 0) ? W0 : (y == 1) ? W1 : W2;
        unsigned short* T = (y == 0) ? T0 : (y == 1) ? T1 : T2;
        if (i < 128 * 128) {
            int k = i >> 7, n = i & 127;
            T[n * 128 + k] = f2bf(W[k * 128 + n]);
        }
        if (y == 0) {
            if (i < 1024) stats[i] = 0.f;
            if (i < 512)  bhist[i] = 0;
        }
    } else {
        for (int c = i; c < N * 16; c += 64 * 256) {
            int node = c >> 4, f = c & 15;
            xp[c] = (f < N_CLASS) ? f2bf(x[node * N_CLASS + f]) : (unsigned short)0;
        }
    }
}

// ==== layer-1 gather on bf16 padded rows (3.2MB -> per-XCD L2-resident) =====
__global__ void gather10_k(const unsigned short* __restrict__ XP, const int* __restrict__ col,
                           const int* __restrict__ rp, const int* __restrict__ cnt,
                           float* __restrict__ out, int N) {
    int t = blockIdx.x * 256 + threadIdx.x;
    int node = t >> 4, f = t & 15;
    if (node >= N) return;
    int start = rp[node], deg = cnt[node];
    float acc = bf2f(XP[node * 16 + f]);
    int j = 0;
    for (; j + 8 <= deg; j += 8) {
        int s0 = col[start + j],     s1 = col[start + j + 1];
        int s2 = col[start + j + 2], s3 = col[start + j + 3];
        int s4 = col[start + j + 4], s5 = col[start + j + 5];
        int s6 = col[start + j + 6], s7 = col[start + j + 7];
        float v0 = bf2f(XP[s0 * 16 + f]);
        float v1 = bf2f(XP[s1 * 16 + f]);
        float v2 = bf2f(XP[s2 * 16 + f]);
        float v3 = bf2f(XP[s3 * 16 + f]);
        float v4 = bf2f(XP[s4 * 16 + f]);
        float v5 = bf2f(XP[s5 * 16 + f]);
        float v6 = bf2f(XP[s6 * 16 + f]);
        float v7 = bf2f(XP[s7 * 16 + f]);
        acc += v0; acc += v1; acc += v2; acc += v3;
        acc += v4; acc += v5; acc += v6; acc += v7;
    }
    for (; j < deg; ++j)
        acc += bf2f(XP[col[start + j] * 16 + f]);
    out[node * 16 + f] = acc;
}

// ======= pre-activation: R = bnrelu(Z), once per node (N x 128 bf16) ========
__global__ __launch_bounds__(256) void act2_k(
    const unsigned short* __restrict__ Z, unsigned short* __restrict__ R,
    const float* __restrict__ st, const float* __restrict__ g,
    const float* __restrict__ b, int N, float inv_n) {
    __shared__ float sTab[128], hTab[128];
    int tid = threadIdx.x;
    if (tid < 128) {
        float m = st[tid] * inv_n;
        float v = fmaxf(st[128 + tid] * inv_n - m * m, 0.f);
        float s = g[tid] * rsqrtf(v + BN_EPS);
        sTab[tid] = s;
        hTab[tid] = b[tid] - m * s;
    }
    __syncthreads();
    int total = N * 16;                       // uint4 count
    for (int i = blockIdx.x * 256 + tid; i < total; i += gridDim.x * 256) {
        int k8 = (i & 15) * 8;
        uint4 v = ((const uint4*)Z)[i];
        unsigned short* us = (unsigned short*)&v;
#pragma unroll
        for (int j = 0; j < 8; ++j) {
            float f = fmaxf(fmaf(bf2f(us[j]), sTab[k8 + j], hTab[k8 + j]), 0.f);
            us[j] = f2bf(f);
        }
        ((uint4*)R)[i] = v;
    }
}

// == layer-2 gather: pure bf16 sum; wave-scalarized CSR reads, 32-bit index ==
__global__ __launch_bounds__(256) void gather_sum_k(
    const unsigned short* __restrict__ R, const int* __restrict__ col,
    const int* __restrict__ rp, const int* __restrict__ cnt,
    unsigned short* __restrict__ out, int N) {
    int wave = __builtin_amdgcn_readfirstlane((blockIdx.x * 256 + threadIdx.x) >> 6);
    int lane = threadIdx.x & 63;
    if (wave >= N) return;
    int start = __builtin_amdgcn_readfirstlane(rp[wave]);
    int deg   = __builtin_amdgcn_readfirstlane(cnt[wave]);
    const unsigned int* Xv = (const unsigned int*)R;   // 2 bf16 per uint
    unsigned int self = Xv[wave * 64 + lane];
    float a0 = lo_f(self);
    float a1 = hi_f(self);
    int j = 0;
    for (; j + 8 <= deg; j += 8) {
        int n0 = col[start + j],     n1 = col[start + j + 1];
        int n2 = col[start + j + 2], n3 = col[start + j + 3];
        int n4 = col[start + j + 4], n5 = col[start + j + 5];
        int n6 = col[start + j + 6], n7 = col[start + j + 7];
        unsigned int w0 = Xv[n0 * 64 + lane];
        unsigned int w1 = Xv[n1 * 64 + lane];
        unsigned int w2 = Xv[n2 * 64 + lane];
        unsigned int w3 = Xv[n3 * 64 + lane];
        unsigned int w4 = Xv[n4 * 64 + lane];
        unsigned int w5 = Xv[n5 * 64 + lane];
        unsigned int w6 = Xv[n6 * 64 + lane];
        unsigned int w7 = Xv[n7 * 64 + lane];
        a0 += lo_f(w0); a1 += hi_f(w0);
        a0 += lo_f(w1); a1 += hi_f(w1);
        a0 += lo_f(w2); a1 += hi_f(w2);
        a0 += lo_f(w3); a1 += hi_f(w3);
        a0 += lo_f(w4); a1 += hi_f(w4);
        a0 += lo_f(w5); a1 += hi_f(w5);
        a0 += lo_f(w6); a1 += hi_f(w6);
        a0 += lo_f(w7); a1 += hi_f(w7);
    }
    for (; j < deg; ++j) {
        unsigned int v = Xv[col[start + j] * 64 + lane];
        a0 += lo_f(v); a1 += hi_f(v);
    }
    unsigned int o = (unsigned int)f2bf(a0) | ((unsigned int)f2bf(a1) << 16);
    ((unsigned int*)out)[wave * 64 + lane] = o;
}

// == K=10 GEMM (padded [N,16] input) + bias + fp32 col-stats, bf16 output ====
__global__ __launch_bounds__(128) void gemm10_k(
    const float* __restrict__ A, const float* __restrict__ W,
    const float* __restrict__ bias, unsigned short* __restrict__ C,
    float* __restrict__ stOut, int N) {
    __shared__ float rb[16 * 16];
    const int tid = threadIdx.x;
    float wreg[N_CLASS];
#pragma unroll
    for (int k = 0; k < N_CLASS; ++k) wreg[k] = W[k * HIDDEN + tid];
    float bb = bias[tid];
    float s = 0.f, s2 = 0.f;
    for (int r0 = blockIdx.x * 16; r0 < N; r0 += gridDim.x * 16) {
        int nr = min(16, N - r0);
        for (int i = tid; i < nr * 16; i += 128) rb[i] = A[r0 * 16 + i];
        __syncthreads();
        for (int r = 0; r < nr; ++r) {
            float acc = bb;
#pragma unroll
            for (int k = 0; k < N_CLASS; ++k) acc = fmaf(rb[r * 16 + k], wreg[k], acc);
            C[(r0 + r) * HIDDEN + tid] = f2bf(acc);
            s += acc; s2 += acc * acc;
        }
        __syncthreads();
    }
    atomicAdd(stOut + tid, s);
    atomicAdd(stOut + HIDDEN + tid, s2);
}

// ============ MFMA bf16 GEMM: Zout = [bnrelu](Zin) @ W + bias ===============
// LDS trimmed to 52.5KB -> 3 blocks/CU; stats reduction aliases Al post-loop.
template<bool BN>
__global__ __launch_bounds__(256) void gemm_mfma_k(
    const unsigned short* __restrict__ Zin, const unsigned short* __restrict__ Wt,
    const float* __restrict__ bias,
    const float* __restrict__ stIn, const float* __restrict__ gIn,
    const float* __restrict__ tIn,
    unsigned short* __restrict__ Zout, float* __restrict__ stOut,
    int N, float inv_n) {
    __shared__ unsigned short Wl[128 * 136];    // 34816 B
    __shared__ unsigned short Al[64 * 136];     // 17408 B (C buffer + stats scratch)
    __shared__ float sTab[128], hTab[128], biasTab[128];   // 1536 B

    const int tid  = threadIdx.x;
    const int wv   = tid >> 6;
    const int ln   = tid & 63;
    const int half = ln >> 4;
    const int l16  = ln & 15;

    if (tid < 128) {
        biasTab[tid] = bias[tid];
        if (BN) {
            float m = stIn[tid] * inv_n;
            float v = fmaxf(stIn[128 + tid] * inv_n - m * m, 0.f);
            float s = gIn[tid] * rsqrtf(v + BN_EPS);
            sTab[tid] = s;
            hTab[tid] = tIn[tid] - m * s;
        }
    }
    for (int c = tid; c < 2048; c += 256) {
        int n = c >> 4, k8 = c & 15;
        uint4 v = *(const uint4*)(Wt + n * 128 + k8 * 8);
        *(uint4*)(&Wl[n * 136 + k8 * 8]) = v;
    }
    __syncthreads();

    float cs[8], cs2[8];
#pragma unroll
    for (int i = 0; i < 8; ++i) { cs[i] = 0.f; cs2[i] = 0.f; }

    const int ntiles = (N + 63) >> 6;
    for (int tile = blockIdx.x; tile < ntiles; tile += gridDim.x) {
        const int r0 = tile * 64;
        for (int c = tid; c < 1024; c += 256) {
            int r = c >> 4, k8 = c & 15;
            int gr = r0 + r; if (gr >= N) gr = N - 1;
            uint4 v = *(const uint4*)(Zin + gr * 128 + k8 * 8);
            if (BN) {
                unsigned short* us = (unsigned short*)&v;
                int kb = k8 * 8;
#pragma unroll
                for (int j = 0; j < 8; ++j) {
                    float f = fmaxf(fmaf(bf2f(us[j]), sTab[kb + j], hTab[kb + j]), 0.f);
                    us[j] = f2bf(f);
                }
            }
            *(uint4*)(&Al[r * 136 + k8 * 8]) = v;
        }
        __syncthreads();

        short8 afrag[4];
        const int arow = wv * 16 + l16;
#pragma unroll
        for (int s = 0; s < 4; ++s)
            afrag[s] = *(const short8*)(&Al[arow * 136 + s * 32 + half * 8]);
        __syncthreads();

#pragma unroll
        for (int ct = 0; ct < 8; ++ct) {
            floatx4 acc = {0.f, 0.f, 0.f, 0.f};
            const int bn_ = ct * 16 + l16;
#pragma unroll
            for (int s = 0; s < 4; ++s) {
                short8 bfrag = *(const short8*)(&Wl[bn_ * 136 + s * 32 + half * 8]);
                acc = __builtin_amdgcn_mfma_f32_16x16x32_bf16(afrag[s], bfrag, acc, 0, 0, 0);
            }
            float bcol = biasTab[bn_];
#pragma unroll
            for (int r = 0; r < 4; ++r) {
                int lrow = wv * 16 + half * 4 + r;
                float val = acc[r] + bcol;
                if (r0 + lrow < N) { cs[ct] += val; cs2[ct] += val * val; }
                Al[lrow * 136 + bn_] = f2bf(val);
            }
        }
        __syncthreads();

        for (int c = tid; c < 1024; c += 256) {
            int r = c >> 4, k8 = c & 15;
            int gr = r0 + r;
            if (gr < N)
                *(uint4*)(Zout + gr * 128 + k8 * 8) = *(const uint4*)(&Al[r * 136 + k8 * 8]);
        }
        __syncthreads();
    }

    // stats reduction in Al-aliased scratch (Al dead after last writeback+sync)
    float* red = (float*)Al;                   // [0..127]=sum, [128..255]=sumsq
    if (tid < 256) red[tid] = 0.f;
    __syncthreads();
#pragma unroll
    for (int ct = 0; ct < 8; ++ct) {
        float a = cs[ct], b = cs2[ct];
        a += __shfl_xor(a, 16); a += __shfl_xor(a, 32);
        b += __shfl_xor(b, 16); b += __shfl_xor(b, 32);
        if (half == 0) {
            atomicAdd(&red[ct * 16 + l16], a);
            atomicAdd(&red[128 + ct * 16 + l16], b);
        }
    }
    __syncthreads();
    if (tid < 128) {
        atomicAdd(stOut + tid, red[tid]);
        atomicAdd(stOut + 128 + tid, red[128 + tid]);
    }
}

// ==== final: BN+ReLU -> @wf + bf -> log_softmax, MFMA (wf padded 10->16) ====
__global__ __launch_bounds__(256) void final_mfma_k(
    const unsigned short* __restrict__ Z, const float* __restrict__ st,
    const float* __restrict__ g, const float* __restrict__ b,
    const float* __restrict__ wf, const float* __restrict__ bfc,
    float* __restrict__ out, int N, float inv_n) {
    __shared__ unsigned short Al[64 * 136];     // 17.4 KB
    __shared__ unsigned short Bl[16 * 136];     // 4.4 KB
    __shared__ float sTab[128], hTab[128], biasTab[16];

    const int tid  = threadIdx.x;
    const int wv   = tid >> 6;
    const int ln   = tid & 63;
    const int half = ln >> 4;
    const int l16  = ln & 15;

    if (tid < 128) {
        float m = st[tid] * inv_n;
        float v = fmaxf(st[128 + tid] * inv_n - m * m, 0.f);
        float s = g[tid] * rsqrtf(v + BN_EPS);
        sTab[tid] = s;
        hTab[tid] = b[tid] - m * s;
    }
    if (tid < 16) biasTab[tid] = (tid < N_CLASS) ? bfc[tid] : -3.0e38f;
    {   // Bl[n][k] = f2bf(wf[k][n]) for n<10, else 0;  16 rows x 128 k
        int n = tid >> 4, k8 = (tid & 15) * 8;
        uint4 v;
        unsigned short* us = (unsigned short*)&v;
#pragma unroll
        for (int j = 0; j < 8; ++j)
            us[j] = (n < N_CLASS) ? f2bf(wf[(k8 + j) * N_CLASS + n]) : (unsigned short)0;
        *(uint4*)(&Bl[n * 136 + k8]) = v;
    }
    __syncthreads();

    short8 bfrag[4];
#pragma unroll
    for (int s = 0; s < 4; ++s)
        bfrag[s] = *(const short8*)(&Bl[l16 * 136 + s * 32 + half * 8]);

    const int ntiles = (N + 63) >> 6;
    for (int tile = blockIdx.x; tile < ntiles; tile += gridDim.x) {
        const int r0 = tile * 64;
        for (int c = tid; c < 1024; c += 256) {
            int r = c >> 4, k8 = c & 15;
            int gr = r0 + r; if (gr >= N) gr = N - 1;
            uint4 v = *(const uint4*)(Z + gr * 128 + k8 * 8);
            unsigned short* us = (unsigned short*)&v;
            int kb = k8 * 8;
#pragma unroll
            for (int j = 0; j < 8; ++j) {
                float f = fmaxf(fmaf(bf2f(us[j]), sTab[kb + j], hTab[kb + j]), 0.f);
                us[j] = f2bf(f);
            }
            *(uint4*)(&Al[r * 136 + k8 * 8]) = v;
        }
        __syncthreads();

        short8 afrag[4];
        const int arow = wv * 16 + l16;
#pragma unroll
        for (int s = 0; s < 4; ++s)
            afrag[s] = *(const short8*)(&Al[arow * 136 + s * 32 + half * 8]);
        __syncthreads();    // Al free for next tile's staging

        floatx4 acc = {0.f, 0.f, 0.f, 0.f};
#pragma unroll
        for (int s = 0; s < 4; ++s)
            acc = __builtin_amdgcn_mfma_f32_16x16x32_bf16(afrag[s], bfrag[s], acc, 0, 0, 0);

        float bcol = biasTab[l16];
#pragma unroll
        for (int r = 0; r < 4; ++r) {
            float lg = acc[r] + bcol;                 // -3e38 for pad cols
            float mx = lg;
            mx = fmaxf(mx, __shfl_xor(mx, 1));
            mx = fmaxf(mx, __shfl_xor(mx, 2));
            mx = fmaxf(mx, __shfl_xor(mx, 4));
            mx = fmaxf(mx, __shfl_xor(mx, 8));
            float p = __expf(lg - mx);                // pad cols -> 0
            float se = p;
            se += __shfl_xor(se, 1);
            se += __shfl_xor(se, 2);
            se += __shfl_xor(se, 4);
            se += __shfl_xor(se, 8);
            float ls = __logf(se);
            int grow = r0 + wv * 16 + half * 4 + r;
            if (l16 < N_CLASS && grow < N)
                out[grow * N_CLASS + l16] = lg - mx - ls;
        }
    }
}

// ===========================================================================

extern "C" void kernel_launch(void* const* d_in, const int* in_sizes, int n_in,
                              void* d_out, int out_size, void* d_ws, size_t ws_size,
                              hipStream_t stream) {
    const float* x   = (const float*)d_in[0];
    const float* w11 = (const float*)d_in[2];
    const float* b11 = (const float*)d_in[3];
    const float* g11 = (const float*)d_in[4];
    const float* t11 = (const float*)d_in[5];
    const float* w12 = (const float*)d_in[6];
    const float* b12 = (const float*)d_in[7];
    const float* g12 = (const float*)d_in[8];
    const float* t12 = (const float*)d_in[9];
    const float* w21 = (const float*)d_in[10];
    const float* b21 = (const float*)d_in[11];
    const float* g21 = (const float*)d_in[12];
    const float* t21 = (const float*)d_in[13];
    const float* w22 = (const float*)d_in[14];
    const float* b22 = (const float*)d_in[15];
    const float* g22 = (const float*)d_in[16];
    const float* t22 = (const float*)d_in[17];
    const float* wf  = (const float*)d_in[18];
    const float* bf  = (const float*)d_in[19];
    const int*   ei  = (const int*)d_in[20];

    const int N = in_sizes[0] / N_CLASS;      // 100000
    const int E = in_sizes[1];                // 1600000
    const float inv_n = 1.0f / (float)N;
    const int NBK = (N + 255) >> 8;           // 391 buckets (<= 512)

    // ---- workspace layout (16B-aligned sections) ----
    char* base = (char*)d_ws;
    size_t off = 0;
    auto take = [&](size_t bytes) { void* p = base + off; off += (bytes + 15) & ~(size_t)15; return p; };
    float*          stats   = (float*)take(1024 * 4);
    unsigned short* xp      = (unsigned short*)take((size_t)N * 16 * 2);
    float*          h0      = (float*)take((size_t)N * 16 * 4);
    int*            cnt     = (int*)take((size_t)N * 4);
    int*            row_ptr = (int*)take((size_t)N * 4);
    int*            bhist   = (int*)take(512 * 4);
    int*            bstart  = (int*)take(520 * 4);
    int*            bcur    = (int*)take(512 * 4);
    unsigned int*   pairs   = (unsigned int*)take((size_t)E * 4);
    int*            col     = (int*)take((size_t)E * 4);
    unsigned short* bufA    = (unsigned short*)take((size_t)N * HIDDEN * 2);
    unsigned short* bufB    = (unsigned short*)take((size_t)N * HIDDEN * 2);
    unsigned short* bufC    = (unsigned short*)take((size_t)N * HIDDEN * 2);
    unsigned short* Wt1     = (unsigned short*)take(128 * 128 * 2);
    unsigned short* Wt2     = (unsigned short*)take(128 * 128 * 2);
    unsigned short* Wt3     = (unsigned short*)take(128 * 128 * 2);

    // ---- prep: weights->bf16^T, zero stats/bhist, pad x->xp (one dispatch) --
    prep_k<<<dim3(64, 4), 256, 0, stream>>>(w12, w21, w22, Wt1, Wt2, Wt3,
                                            stats, bhist, x, xp, N);

    // ---- bucketed CSR build (no per-edge global atomics, packed pairs) ----
    bhist_k<<<256, 512, 0, stream>>>(ei, bhist, E);
    bscan_k<<<1, 512, 0, stream>>>(bhist, bstart, bcur, NBK);
    bscatter_k<<<256, 512, 0, stream>>>(ei, bcur, pairs, E);
    bcsr_k<<<NBK, 512, 0, stream>>>(pairs, bstart, row_ptr, cnt, col, N);

    // ---- layer 1 ----
    gather10_k<<<(N * 16 + 255) / 256, 256, 0, stream>>>(xp, col, row_ptr, cnt, h0, N);
    gemm10_k<<<512, 128, 0, stream>>>(h0, w11, b11, bufA, stats, N);            // Z1 + stats0
    gemm_mfma_k<true><<<768, 256, 0, stream>>>(bufA, Wt1, b12, stats, g11, t11,
                                               bufB, stats + 256, N, inv_n);    // Z2 + stats1

    // ---- layer 2 aggregation: activate once per node, then pure-sum gather --
    act2_k<<<3125, 256, 0, stream>>>(bufB, bufC, stats + 256, g12, t12, N, inv_n);
    gather_sum_k<<<(N * 64 + 255) / 256, 256, 0, stream>>>(bufC, col, row_ptr, cnt,
                                                           bufA, N);

    // ---- layer 2 MLP ----
    gemm_mfma_k<false><<<768, 256, 0, stream>>>(bufA, Wt2, b21, nullptr, nullptr, nullptr,
                                                bufB, stats + 512, N, inv_n);   // Z3 + stats2
    gemm_mfma_k<true><<<768, 256, 0, stream>>>(bufB, Wt3, b22, stats + 512, g21, t21,
                                               bufA, stats + 768, N, inv_n);    // Z4 + stats3

    // ---- final linear + log_softmax (BN4+ReLU fused, MFMA) ----
    final_mfma_k<<<782, 256, 0, stream>>>(bufA, stats + 768, g22, t22,
                                          wf, bf, (float*)d_out, N, inv_n);
}

// Round 11
// 404.748 us; speedup vs baseline: 1.0891x; 1.0891x over previous
//
#include <hip/hip_runtime.h>

#define N_CLASS 10
#define HIDDEN 128
#define BN_EPS 1e-5f

typedef short short8 __attribute__((ext_vector_type(8)));   // 8 bf16 in 4 VGPRs
typedef float floatx4 __attribute__((ext_vector_type(4)));

__device__ __forceinline__ float bf2f(unsigned short u) {
    unsigned int x = ((unsigned int)u) << 16;
    float f; __builtin_memcpy(&f, &x, 4); return f;
}
__device__ __forceinline__ unsigned short f2bf(float f) {
    unsigned int x; __builtin_memcpy(&x, &f, 4);
    x += 0x7FFFu + ((x >> 16) & 1u);          // round-to-nearest-even
    return (unsigned short)(x >> 16);
}
// exact bf16 unpack of a packed uint, 1 VALU op each
__device__ __forceinline__ float lo_f(unsigned int u) {
    unsigned int x = u << 16; float f; __builtin_memcpy(&f, &x, 4); return f;
}
__device__ __forceinline__ float hi_f(unsigned int u) {
    unsigned int x = u & 0xffff0000u; float f; __builtin_memcpy(&f, &x, 4); return f;
}

// ================= bucketed CSR build (no per-edge global atomics) ==========
// bucket = dst >> 8  (256 dsts per bucket; NBK = ceil(N/256) = 391 <= 512)
// pairs entry packed: src (low 24 bits, src < 2^17) | dst&255 (high 8 bits)

__global__ __launch_bounds__(512) void bhist_k(const int* __restrict__ ei,
                                               int* __restrict__ bhist, int E) {
    __shared__ int h[512];
    int tid = threadIdx.x;
    h[tid] = 0;
    __syncthreads();
    for (int e = blockIdx.x * 512 + tid; e < E; e += gridDim.x * 512)
        atomicAdd(&h[((unsigned)ei[E + e]) >> 8], 1);
    __syncthreads();
    if (h[tid]) atomicAdd(&bhist[tid], h[tid]);
}

__global__ __launch_bounds__(512) void bscan_k(const int* __restrict__ bhist,
                                               int* __restrict__ bstart,
                                               int* __restrict__ bcur, int NBK) {
    __shared__ int sm[512];
    int t = threadIdx.x;
    sm[t] = (t < NBK) ? bhist[t] : 0;
    __syncthreads();
    for (int off = 1; off < 512; off <<= 1) {
        int u = (t >= off) ? sm[t - off] : 0;
        __syncthreads();
        sm[t] += u;
        __syncthreads();
    }
    int excl = (t == 0) ? 0 : sm[t - 1];
    if (t <= NBK) bstart[t] = excl;
    if (t < NBK)  bcur[t]   = excl;
}

__global__ __launch_bounds__(512) void bscatter_k(const int* __restrict__ ei,
                                                  int* __restrict__ bcur,
                                                  unsigned int* __restrict__ pairs, int E) {
    __shared__ int h[512], base[512], cur[512];
    int tid = threadIdx.x;
    h[tid] = 0; cur[tid] = 0;
    __syncthreads();
    int chunk = (E + gridDim.x - 1) / gridDim.x;
    int e0 = blockIdx.x * chunk;
    int e1 = min(e0 + chunk, E);
    for (int e = e0 + tid; e < e1; e += 512)
        atomicAdd(&h[((unsigned)ei[E + e]) >> 8], 1);
    __syncthreads();
    base[tid] = h[tid] ? atomicAdd(&bcur[tid], h[tid]) : 0;
    __syncthreads();
    for (int e = e0 + tid; e < e1; e += 512) {
        unsigned int s = (unsigned int)ei[e];
        unsigned int d = (unsigned int)ei[E + e];
        int bk = d >> 8;
        int r = atomicAdd(&cur[bk], 1);      // LDS
        pairs[base[bk] + r] = s | ((d & 255u) << 24);
    }
}

__global__ __launch_bounds__(512) void bcsr_k(const unsigned int* __restrict__ pairs,
                                              const int* __restrict__ bstart,
                                              int* __restrict__ row_ptr,
                                              int* __restrict__ cnt,
                                              int* __restrict__ col, int N) {
    __shared__ int h[256], sc[256], cur[256];
    int tid = threadIdx.x;
    if (tid < 256) { h[tid] = 0; cur[tid] = 0; }
    __syncthreads();
    int b = blockIdx.x, lo = b << 8;
    int s = bstart[b], e = bstart[b + 1];
    for (int i = s + tid; i < e; i += 512)
        atomicAdd(&h[pairs[i] >> 24], 1);    // LDS
    __syncthreads();
    if (tid < 256) sc[tid] = h[tid];
    __syncthreads();
    for (int off = 1; off < 256; off <<= 1) {
        int u = (tid < 256 && tid >= off) ? sc[tid - off] : 0;
        __syncthreads();
        if (tid < 256) sc[tid] += u;
        __syncthreads();
    }
    if (tid < 256) {
        int d = lo + tid;
        if (d < N) { cnt[d] = h[tid]; row_ptr[d] = s + sc[tid] - h[tid]; }
        sc[tid] -= h[tid];                   // exclusive, for the fill below
    }
    __syncthreads();
    for (int i = s + tid; i < e; i += 512) {
        unsigned int p = pairs[i];
        int d = p >> 24;
        int r = atomicAdd(&cur[d], 1);       // LDS
        col[s + sc[d] + r] = (int)(p & 0xFFFFFFu);
    }
}

// === prep: Wt bf16 transpose x3 + zero stats/bhist ==========================
__global__ void prep_k(const float* __restrict__ W0, const float* __restrict__ W1,
                       const float* __restrict__ W2,
                       unsigned short* __restrict__ T0, unsigned short* __restrict__ T1,
                       unsigned short* __restrict__ T2,
                       float* __restrict__ stats, int* __restrict__ bhist) {
    int y = blockIdx.y;
    int i = blockIdx.x * 256 + threadIdx.x;
    const float* W = (y == 0) ? W0 : (y == 1) ? W1 : W2;
    unsigned short* T = (y == 0) ? T0 : (y == 1) ? T1 : T2;
    if (i < 128 * 128) {
        int k = i >> 7, n = i & 127;
        T[n * 128 + k] = f2bf(W[k * 128 + n]);
    }
    if (y == 0) {
        if (i < 1024) stats[i] = 0.f;
        if (i < 512)  bhist[i] = 0;
    }
}

// ====== pad x [N,10] fp32 -> xp [N,16] bf16, full grid (1 elem/thread) ======
__global__ void padx_k(const float* __restrict__ X, unsigned short* __restrict__ XP, int N) {
    int i = blockIdx.x * 256 + threadIdx.x;
    if (i >= N * 16) return;
    int node = i >> 4, f = i & 15;
    XP[i] = (f < N_CLASS) ? f2bf(X[node * N_CLASS + f]) : (unsigned short)0;
}

// ==== layer-1 gather on bf16 padded rows (3.2MB -> per-XCD L2-resident) =====
__global__ void gather10_k(const unsigned short* __restrict__ XP, const int* __restrict__ col,
                           const int* __restrict__ rp, const int* __restrict__ cnt,
                           float* __restrict__ out, int N) {
    int t = blockIdx.x * 256 + threadIdx.x;
    int node = t >> 4, f = t & 15;
    if (node >= N) return;
    int start = rp[node], deg = cnt[node];
    float acc = bf2f(XP[node * 16 + f]);
    int j = 0;
    for (; j + 8 <= deg; j += 8) {
        int s0 = col[start + j],     s1 = col[start + j + 1];
        int s2 = col[start + j + 2], s3 = col[start + j + 3];
        int s4 = col[start + j + 4], s5 = col[start + j + 5];
        int s6 = col[start + j + 6], s7 = col[start + j + 7];
        float v0 = bf2f(XP[s0 * 16 + f]);
        float v1 = bf2f(XP[s1 * 16 + f]);
        float v2 = bf2f(XP[s2 * 16 + f]);
        float v3 = bf2f(XP[s3 * 16 + f]);
        float v4 = bf2f(XP[s4 * 16 + f]);
        float v5 = bf2f(XP[s5 * 16 + f]);
        float v6 = bf2f(XP[s6 * 16 + f]);
        float v7 = bf2f(XP[s7 * 16 + f]);
        acc += v0; acc += v1; acc += v2; acc += v3;
        acc += v4; acc += v5; acc += v6; acc += v7;
    }
    for (; j < deg; ++j)
        acc += bf2f(XP[col[start + j] * 16 + f]);
    out[node * 16 + f] = acc;
}

// ======= pre-activation: R = bnrelu(Z), once per node (N x 128 bf16) ========
__global__ __launch_bounds__(256) void act2_k(
    const unsigned short* __restrict__ Z, unsigned short* __restrict__ R,
    const float* __restrict__ st, const float* __restrict__ g,
    const float* __restrict__ b, int N, float inv_n) {
    __shared__ float sTab[128], hTab[128];
    int tid = threadIdx.x;
    if (tid < 128) {
        float m = st[tid] * inv_n;
        float v = fmaxf(st[128 + tid] * inv_n - m * m, 0.f);
        float s = g[tid] * rsqrtf(v + BN_EPS);
        sTab[tid] = s;
        hTab[tid] = b[tid] - m * s;
    }
    __syncthreads();
    int total = N * 16;                       // uint4 count
    for (int i = blockIdx.x * 256 + tid; i < total; i += gridDim.x * 256) {
        int k8 = (i & 15) * 8;
        uint4 v = ((const uint4*)Z)[i];
        unsigned short* us = (unsigned short*)&v;
#pragma unroll
        for (int j = 0; j < 8; ++j) {
            float f = fmaxf(fmaf(bf2f(us[j]), sTab[k8 + j], hTab[k8 + j]), 0.f);
            us[j] = f2bf(f);
        }
        ((uint4*)R)[i] = v;
    }
}

// == layer-2 gather: pure bf16 sum; wave-scalarized CSR reads, 32-bit index ==
__global__ __launch_bounds__(256) void gather_sum_k(
    const unsigned short* __restrict__ R, const int* __restrict__ col,
    const int* __restrict__ rp, const int* __restrict__ cnt,
    unsigned short* __restrict__ out, int N) {
    int wave = __builtin_amdgcn_readfirstlane((blockIdx.x * 256 + threadIdx.x) >> 6);
    int lane = threadIdx.x & 63;
    if (wave >= N) return;
    int start = __builtin_amdgcn_readfirstlane(rp[wave]);
    int deg   = __builtin_amdgcn_readfirstlane(cnt[wave]);
    const unsigned int* Xv = (const unsigned int*)R;   // 2 bf16 per uint
    unsigned int self = Xv[wave * 64 + lane];
    float a0 = lo_f(self);
    float a1 = hi_f(self);
    int j = 0;
    for (; j + 8 <= deg; j += 8) {
        int n0 = col[start + j],     n1 = col[start + j + 1];
        int n2 = col[start + j + 2], n3 = col[start + j + 3];
        int n4 = col[start + j + 4], n5 = col[start + j + 5];
        int n6 = col[start + j + 6], n7 = col[start + j + 7];
        unsigned int w0 = Xv[n0 * 64 + lane];
        unsigned int w1 = Xv[n1 * 64 + lane];
        unsigned int w2 = Xv[n2 * 64 + lane];
        unsigned int w3 = Xv[n3 * 64 + lane];
        unsigned int w4 = Xv[n4 * 64 + lane];
        unsigned int w5 = Xv[n5 * 64 + lane];
        unsigned int w6 = Xv[n6 * 64 + lane];
        unsigned int w7 = Xv[n7 * 64 + lane];
        a0 += lo_f(w0); a1 += hi_f(w0);
        a0 += lo_f(w1); a1 += hi_f(w1);
        a0 += lo_f(w2); a1 += hi_f(w2);
        a0 += lo_f(w3); a1 += hi_f(w3);
        a0 += lo_f(w4); a1 += hi_f(w4);
        a0 += lo_f(w5); a1 += hi_f(w5);
        a0 += lo_f(w6); a1 += hi_f(w6);
        a0 += lo_f(w7); a1 += hi_f(w7);
    }
    for (; j < deg; ++j) {
        unsigned int v = Xv[col[start + j] * 64 + lane];
        a0 += lo_f(v); a1 += hi_f(v);
    }
    unsigned int o = (unsigned int)f2bf(a0) | ((unsigned int)f2bf(a1) << 16);
    ((unsigned int*)out)[wave * 64 + lane] = o;
}

// == K=10 GEMM (padded [N,16] input) + bias + fp32 col-stats, bf16 output ====
__global__ __launch_bounds__(128) void gemm10_k(
    const float* __restrict__ A, const float* __restrict__ W,
    const float* __restrict__ bias, unsigned short* __restrict__ C,
    float* __restrict__ stOut, int N) {
    __shared__ float rb[16 * 16];
    const int tid = threadIdx.x;
    float wreg[N_CLASS];
#pragma unroll
    for (int k = 0; k < N_CLASS; ++k) wreg[k] = W[k * HIDDEN + tid];
    float bb = bias[tid];
    float s = 0.f, s2 = 0.f;
    for (int r0 = blockIdx.x * 16; r0 < N; r0 += gridDim.x * 16) {
        int nr = min(16, N - r0);
        for (int i = tid; i < nr * 16; i += 128) rb[i] = A[r0 * 16 + i];
        __syncthreads();
        for (int r = 0; r < nr; ++r) {
            float acc = bb;
#pragma unroll
            for (int k = 0; k < N_CLASS; ++k) acc = fmaf(rb[r * 16 + k], wreg[k], acc);
            C[(r0 + r) * HIDDEN + tid] = f2bf(acc);
            s += acc; s2 += acc * acc;
        }
        __syncthreads();
    }
    atomicAdd(stOut + tid, s);
    atomicAdd(stOut + HIDDEN + tid, s2);
}

// ============ MFMA bf16 GEMM: Zout = [bnrelu](Zin) @ W + bias ===============
// LDS 52.5KB + __launch_bounds__(256,3) -> target 3 blocks/CU, grid 768.
template<bool BN>
__global__ __launch_bounds__(256, 3) void gemm_mfma_k(
    const unsigned short* __restrict__ Zin, const unsigned short* __restrict__ Wt,
    const float* __restrict__ bias,
    const float* __restrict__ stIn, const float* __restrict__ gIn,
    const float* __restrict__ tIn,
    unsigned short* __restrict__ Zout, float* __restrict__ stOut,
    int N, float inv_n) {
    __shared__ unsigned short Wl[128 * 136];    // 34816 B
    __shared__ unsigned short Al[64 * 136];     // 17408 B (C buffer + stats scratch)
    __shared__ float sTab[128], hTab[128], biasTab[128];   // 1536 B

    const int tid  = threadIdx.x;
    const int wv   = tid >> 6;
    const int ln   = tid & 63;
    const int half = ln >> 4;
    const int l16  = ln & 15;

    if (tid < 128) {
        biasTab[tid] = bias[tid];
        if (BN) {
            float m = stIn[tid] * inv_n;
            float v = fmaxf(stIn[128 + tid] * inv_n - m * m, 0.f);
            float s = gIn[tid] * rsqrtf(v + BN_EPS);
            sTab[tid] = s;
            hTab[tid] = tIn[tid] - m * s;
        }
    }
    for (int c = tid; c < 2048; c += 256) {
        int n = c >> 4, k8 = c & 15;
        uint4 v = *(const uint4*)(Wt + n * 128 + k8 * 8);
        *(uint4*)(&Wl[n * 136 + k8 * 8]) = v;
    }
    __syncthreads();

    float cs[8], cs2[8];
#pragma unroll
    for (int i = 0; i < 8; ++i) { cs[i] = 0.f; cs2[i] = 0.f; }

    const int ntiles = (N + 63) >> 6;
    for (int tile = blockIdx.x; tile < ntiles; tile += gridDim.x) {
        const int r0 = tile * 64;
        for (int c = tid; c < 1024; c += 256) {
            int r = c >> 4, k8 = c & 15;
            int gr = r0 + r; if (gr >= N) gr = N - 1;
            uint4 v = *(const uint4*)(Zin + gr * 128 + k8 * 8);
            if (BN) {
                unsigned short* us = (unsigned short*)&v;
                int kb = k8 * 8;
#pragma unroll
                for (int j = 0; j < 8; ++j) {
                    float f = fmaxf(fmaf(bf2f(us[j]), sTab[kb + j], hTab[kb + j]), 0.f);
                    us[j] = f2bf(f);
                }
            }
            *(uint4*)(&Al[r * 136 + k8 * 8]) = v;
        }
        __syncthreads();

        short8 afrag[4];
        const int arow = wv * 16 + l16;
#pragma unroll
        for (int s = 0; s < 4; ++s)
            afrag[s] = *(const short8*)(&Al[arow * 136 + s * 32 + half * 8]);
        __syncthreads();

#pragma unroll
        for (int ct = 0; ct < 8; ++ct) {
            floatx4 acc = {0.f, 0.f, 0.f, 0.f};
            const int bn_ = ct * 16 + l16;
#pragma unroll
            for (int s = 0; s < 4; ++s) {
                short8 bfrag = *(const short8*)(&Wl[bn_ * 136 + s * 32 + half * 8]);
                acc = __builtin_amdgcn_mfma_f32_16x16x32_bf16(afrag[s], bfrag, acc, 0, 0, 0);
            }
            float bcol = biasTab[bn_];
#pragma unroll
            for (int r = 0; r < 4; ++r) {
                int lrow = wv * 16 + half * 4 + r;
                float val = acc[r] + bcol;
                if (r0 + lrow < N) { cs[ct] += val; cs2[ct] += val * val; }
                Al[lrow * 136 + bn_] = f2bf(val);
            }
        }
        __syncthreads();

        for (int c = tid; c < 1024; c += 256) {
            int r = c >> 4, k8 = c & 15;
            int gr = r0 + r;
            if (gr < N)
                *(uint4*)(Zout + gr * 128 + k8 * 8) = *(const uint4*)(&Al[r * 136 + k8 * 8]);
        }
        __syncthreads();
    }

    // stats reduction in Al-aliased scratch (Al dead after last writeback+sync)
    float* red = (float*)Al;                   // [0..127]=sum, [128..255]=sumsq
    if (tid < 256) red[tid] = 0.f;
    __syncthreads();
#pragma unroll
    for (int ct = 0; ct < 8; ++ct) {
        float a = cs[ct], b = cs2[ct];
        a += __shfl_xor(a, 16); a += __shfl_xor(a, 32);
        b += __shfl_xor(b, 16); b += __shfl_xor(b, 32);
        if (half == 0) {
            atomicAdd(&red[ct * 16 + l16], a);
            atomicAdd(&red[128 + ct * 16 + l16], b);
        }
    }
    __syncthreads();
    if (tid < 128) {
        atomicAdd(stOut + tid, red[tid]);
        atomicAdd(stOut + 128 + tid, red[128 + tid]);
    }
}

// ==== final: BN+ReLU -> @wf + bf -> log_softmax, MFMA (wf padded 10->16) ====
__global__ __launch_bounds__(256) void final_mfma_k(
    const unsigned short* __restrict__ Z, const float* __restrict__ st,
    const float* __restrict__ g, const float* __restrict__ b,
    const float* __restrict__ wf, const float* __restrict__ bfc,
    float* __restrict__ out, int N, float inv_n) {
    __shared__ unsigned short Al[64 * 136];     // 17.4 KB
    __shared__ unsigned short Bl[16 * 136];     // 4.4 KB
    __shared__ float sTab[128], hTab[128], biasTab[16];

    const int tid  = threadIdx.x;
    const int wv   = tid >> 6;
    const int ln   = tid & 63;
    const int half = ln >> 4;
    const int l16  = ln & 15;

    if (tid < 128) {
        float m = st[tid] * inv_n;
        float v = fmaxf(st[128 + tid] * inv_n - m * m, 0.f);
        float s = g[tid] * rsqrtf(v + BN_EPS);
        sTab[tid] = s;
        hTab[tid] = b[tid] - m * s;
    }
    if (tid < 16) biasTab[tid] = (tid < N_CLASS) ? bfc[tid] : -3.0e38f;
    {   // Bl[n][k] = f2bf(wf[k][n]) for n<10, else 0;  16 rows x 128 k
        int n = tid >> 4, k8 = (tid & 15) * 8;
        uint4 v;
        unsigned short* us = (unsigned short*)&v;
#pragma unroll
        for (int j = 0; j < 8; ++j)
            us[j] = (n < N_CLASS) ? f2bf(wf[(k8 + j) * N_CLASS + n]) : (unsigned short)0;
        *(uint4*)(&Bl[n * 136 + k8]) = v;
    }
    __syncthreads();

    short8 bfrag[4];
#pragma unroll
    for (int s = 0; s < 4; ++s)
        bfrag[s] = *(const short8*)(&Bl[l16 * 136 + s * 32 + half * 8]);

    const int ntiles = (N + 63) >> 6;
    for (int tile = blockIdx.x; tile < ntiles; tile += gridDim.x) {
        const int r0 = tile * 64;
        for (int c = tid; c < 1024; c += 256) {
            int r = c >> 4, k8 = c & 15;
            int gr = r0 + r; if (gr >= N) gr = N - 1;
            uint4 v = *(const uint4*)(Z + gr * 128 + k8 * 8);
            unsigned short* us = (unsigned short*)&v;
            int kb = k8 * 8;
#pragma unroll
            for (int j = 0; j < 8; ++j) {
                float f = fmaxf(fmaf(bf2f(us[j]), sTab[kb + j], hTab[kb + j]), 0.f);
                us[j] = f2bf(f);
            }
            *(uint4*)(&Al[r * 136 + k8 * 8]) = v;
        }
        __syncthreads();

        short8 afrag[4];
        const int arow = wv * 16 + l16;
#pragma unroll
        for (int s = 0; s < 4; ++s)
            afrag[s] = *(const short8*)(&Al[arow * 136 + s * 32 + half * 8]);
        __syncthreads();    // Al free for next tile's staging

        floatx4 acc = {0.f, 0.f, 0.f, 0.f};
#pragma unroll
        for (int s = 0; s < 4; ++s)
            acc = __builtin_amdgcn_mfma_f32_16x16x32_bf16(afrag[s], bfrag[s], acc, 0, 0, 0);

        float bcol = biasTab[l16];
#pragma unroll
        for (int r = 0; r < 4; ++r) {
            float lg = acc[r] + bcol;                 // -3e38 for pad cols
            float mx = lg;
            mx = fmaxf(mx, __shfl_xor(mx, 1));
            mx = fmaxf(mx, __shfl_xor(mx, 2));
            mx = fmaxf(mx, __shfl_xor(mx, 4));
            mx = fmaxf(mx, __shfl_xor(mx, 8));
            float p = __expf(lg - mx);                // pad cols -> 0
            float se = p;
            se += __shfl_xor(se, 1);
            se += __shfl_xor(se, 2);
            se += __shfl_xor(se, 4);
            se += __shfl_xor(se, 8);
            float ls = __logf(se);
            int grow = r0 + wv * 16 + half * 4 + r;
            if (l16 < N_CLASS && grow < N)
                out[grow * N_CLASS + l16] = lg - mx - ls;
        }
    }
}

// ===========================================================================

extern "C" void kernel_launch(void* const* d_in, const int* in_sizes, int n_in,
                              void* d_out, int out_size, void* d_ws, size_t ws_size,
                              hipStream_t stream) {
    const float* x   = (const float*)d_in[0];
    const float* w11 = (const float*)d_in[2];
    const float* b11 = (const float*)d_in[3];
    const float* g11 = (const float*)d_in[4];
    const float* t11 = (const float*)d_in[5];
    const float* w12 = (const float*)d_in[6];
    const float* b12 = (const float*)d_in[7];
    const float* g12 = (const float*)d_in[8];
    const float* t12 = (const float*)d_in[9];
    const float* w21 = (const float*)d_in[10];
    const float* b21 = (const float*)d_in[11];
    const float* g21 = (const float*)d_in[12];
    const float* t21 = (const float*)d_in[13];
    const float* w22 = (const float*)d_in[14];
    const float* b22 = (const float*)d_in[15];
    const float* g22 = (const float*)d_in[16];
    const float* t22 = (const float*)d_in[17];
    const float* wf  = (const float*)d_in[18];
    const float* bf  = (const float*)d_in[19];
    const int*   ei  = (const int*)d_in[20];

    const int N = in_sizes[0] / N_CLASS;      // 100000
    const int E = in_sizes[1];                // 1600000
    const float inv_n = 1.0f / (float)N;
    const int NBK = (N + 255) >> 8;           // 391 buckets (<= 512)

    // ---- workspace layout (16B-aligned sections) ----
    char* base = (char*)d_ws;
    size_t off = 0;
    auto take = [&](size_t bytes) { void* p = base + off; off += (bytes + 15) & ~(size_t)15; return p; };
    float*          stats   = (float*)take(1024 * 4);
    unsigned short* xp      = (unsigned short*)take((size_t)N * 16 * 2);
    float*          h0      = (float*)take((size_t)N * 16 * 4);
    int*            cnt     = (int*)take((size_t)N * 4);
    int*            row_ptr = (int*)take((size_t)N * 4);
    int*            bhist   = (int*)take(512 * 4);
    int*            bstart  = (int*)take(520 * 4);
    int*            bcur    = (int*)take(512 * 4);
    unsigned int*   pairs   = (unsigned int*)take((size_t)E * 4);
    int*            col     = (int*)take((size_t)E * 4);
    unsigned short* bufA    = (unsigned short*)take((size_t)N * HIDDEN * 2);
    unsigned short* bufB    = (unsigned short*)take((size_t)N * HIDDEN * 2);
    unsigned short* bufC    = (unsigned short*)take((size_t)N * HIDDEN * 2);
    unsigned short* Wt1     = (unsigned short*)take(128 * 128 * 2);
    unsigned short* Wt2     = (unsigned short*)take(128 * 128 * 2);
    unsigned short* Wt3     = (unsigned short*)take(128 * 128 * 2);

    // ---- prep: weights->bf16^T + zero stats/bhist; padx at full grid ----
    prep_k<<<dim3(64, 3), 256, 0, stream>>>(w12, w21, w22, Wt1, Wt2, Wt3,
                                            stats, bhist);
    padx_k<<<(N * 16 + 255) / 256, 256, 0, stream>>>(x, xp, N);

    // ---- bucketed CSR build (no per-edge global atomics, packed pairs) ----
    bhist_k<<<256, 512, 0, stream>>>(ei, bhist, E);
    bscan_k<<<1, 512, 0, stream>>>(bhist, bstart, bcur, NBK);
    bscatter_k<<<256, 512, 0, stream>>>(ei, bcur, pairs, E);
    bcsr_k<<<NBK, 512, 0, stream>>>(pairs, bstart, row_ptr, cnt, col, N);

    // ---- layer 1 ----
    gather10_k<<<(N * 16 + 255) / 256, 256, 0, stream>>>(xp, col, row_ptr, cnt, h0, N);
    gemm10_k<<<512, 128, 0, stream>>>(h0, w11, b11, bufA, stats, N);            // Z1 + stats0
    gemm_mfma_k<true><<<768, 256, 0, stream>>>(bufA, Wt1, b12, stats, g11, t11,
                                               bufB, stats + 256, N, inv_n);    // Z2 + stats1

    // ---- layer 2 aggregation: activate once per node, then pure-sum gather --
    act2_k<<<3125, 256, 0, stream>>>(bufB, bufC, stats + 256, g12, t12, N, inv_n);
    gather_sum_k<<<(N * 64 + 255) / 256, 256, 0, stream>>>(bufC, col, row_ptr, cnt,
                                                           bufA, N);

    // ---- layer 2 MLP ----
    gemm_mfma_k<false><<<768, 256, 0, stream>>>(bufA, Wt2, b21, nullptr, nullptr, nullptr,
                                                bufB, stats + 512, N, inv_n);   // Z3 + stats2
    gemm_mfma_k<true><<<768, 256, 0, stream>>>(bufB, Wt3, b22, stats + 512, g21, t21,
                                               bufA, stats + 768, N, inv_n);    // Z4 + stats3

    // ---- final linear + log_softmax (BN4+ReLU fused, MFMA) ----
    final_mfma_k<<<782, 256, 0, stream>>>(bufA, stats + 768, g22, t22,
                                          wf, bf, (float*)d_out, N, inv_n);
}

// Round 12
// 400.908 us; speedup vs baseline: 1.0995x; 1.0096x over previous
//
#include <hip/hip_runtime.h>

#define N_CLASS 10
#define HIDDEN 128
#define BN_EPS 1e-5f

typedef short short8 __attribute__((ext_vector_type(8)));   // 8 bf16 in 4 VGPRs
typedef float floatx4 __attribute__((ext_vector_type(4)));

__device__ __forceinline__ float bf2f(unsigned short u) {
    unsigned int x = ((unsigned int)u) << 16;
    float f; __builtin_memcpy(&f, &x, 4); return f;
}
__device__ __forceinline__ unsigned short f2bf(float f) {
    unsigned int x; __builtin_memcpy(&x, &f, 4);
    x += 0x7FFFu + ((x >> 16) & 1u);          // round-to-nearest-even
    return (unsigned short)(x >> 16);
}
// exact bf16 unpack of a packed uint, 1 VALU op each
__device__ __forceinline__ float lo_f(unsigned int u) {
    unsigned int x = u << 16; float f; __builtin_memcpy(&f, &x, 4); return f;
}
__device__ __forceinline__ float hi_f(unsigned int u) {
    unsigned int x = u & 0xffff0000u; float f; __builtin_memcpy(&f, &x, 4); return f;
}

// ================= bucketed CSR build (no per-edge global atomics) ==========
// bucket = dst >> 8  (256 dsts per bucket; NBK = ceil(N/256) = 391 <= 512)
// pairs entry packed: src (low 24 bits, src < 2^17) | dst&255 (high 8 bits)
// bhist & bscatter use IDENTICAL chunked edge partitions (grid 256) so the
// per-block histograms in bbase[bucket][block] give exact placement bases.

__global__ __launch_bounds__(512) void bhist_k(const int* __restrict__ ei,
                                               int* __restrict__ bhist,
                                               int* __restrict__ bbase, int E) {
    __shared__ int h[512];
    int tid = threadIdx.x;
    h[tid] = 0;
    __syncthreads();
    int chunk = (E + gridDim.x - 1) / gridDim.x;
    int e0 = blockIdx.x * chunk;
    int e1 = min(e0 + chunk, E);
    for (int e = e0 + tid; e < e1; e += 512)
        atomicAdd(&h[((unsigned)ei[E + e]) >> 8], 1);
    __syncthreads();
    bbase[tid * 256 + blockIdx.x] = h[tid];           // [bucket][block]
    if (h[tid]) atomicAdd(&bhist[tid], h[tid]);
}

__global__ __launch_bounds__(512) void bscan_k(const int* __restrict__ bhist,
                                               int* __restrict__ bstart, int NBK) {
    __shared__ int sm[512];
    int t = threadIdx.x;
    sm[t] = (t < NBK) ? bhist[t] : 0;
    __syncthreads();
    for (int off = 1; off < 512; off <<= 1) {
        int u = (t >= off) ? sm[t - off] : 0;
        __syncthreads();
        sm[t] += u;
        __syncthreads();
    }
    bstart[t] = (t == 0) ? 0 : sm[t - 1];             // all 512 written
    if (t == 0) bstart[512] = sm[511];
}

// per-bucket exclusive scan of the 256 per-block counts, + bucket base
__global__ __launch_bounds__(256) void bscan2_k(int* __restrict__ bbase,
                                                const int* __restrict__ bstart) {
    __shared__ int sm[256];
    int b = blockIdx.x;            // bucket
    int t = threadIdx.x;           // edge-chunk block index
    int v = bbase[b * 256 + t];
    sm[t] = v;
    __syncthreads();
    for (int off = 1; off < 256; off <<= 1) {
        int u = (t >= off) ? sm[t - off] : 0;
        __syncthreads();
        sm[t] += u;
        __syncthreads();
    }
    bbase[b * 256 + t] = bstart[b] + sm[t] - v;       // exclusive
}

__global__ __launch_bounds__(512) void bscatter_k(const int* __restrict__ ei,
                                                  const int* __restrict__ bbase,
                                                  unsigned int* __restrict__ pairs, int E) {
    __shared__ int base[512], cur[512];
    int tid = threadIdx.x;
    base[tid] = bbase[tid * 256 + blockIdx.x];
    cur[tid] = 0;
    __syncthreads();
    int chunk = (E + gridDim.x - 1) / gridDim.x;
    int e0 = blockIdx.x * chunk;
    int e1 = min(e0 + chunk, E);
    for (int e = e0 + tid; e < e1; e += 512) {
        unsigned int s = (unsigned int)ei[e];
        unsigned int d = (unsigned int)ei[E + e];
        int bk = d >> 8;
        int r = atomicAdd(&cur[bk], 1);      // LDS only
        pairs[base[bk] + r] = s | ((d & 255u) << 24);
    }
}

__global__ __launch_bounds__(512) void bcsr_k(const unsigned int* __restrict__ pairs,
                                              const int* __restrict__ bstart,
                                              int* __restrict__ row_ptr,
                                              int* __restrict__ cnt,
                                              int* __restrict__ col, int N) {
    __shared__ int h[256], sc[256], cur[256];
    int tid = threadIdx.x;
    if (tid < 256) { h[tid] = 0; cur[tid] = 0; }
    __syncthreads();
    int b = blockIdx.x, lo = b << 8;
    int s = bstart[b], e = bstart[b + 1];
    for (int i = s + tid; i < e; i += 512)
        atomicAdd(&h[pairs[i] >> 24], 1);    // LDS
    __syncthreads();
    if (tid < 256) sc[tid] = h[tid];
    __syncthreads();
    for (int off = 1; off < 256; off <<= 1) {
        int u = (tid < 256 && tid >= off) ? sc[tid - off] : 0;
        __syncthreads();
        if (tid < 256) sc[tid] += u;
        __syncthreads();
    }
    if (tid < 256) {
        int d = lo + tid;
        if (d < N) { cnt[d] = h[tid]; row_ptr[d] = s + sc[tid] - h[tid]; }
        sc[tid] -= h[tid];                   // exclusive, for the fill below
    }
    __syncthreads();
    for (int i = s + tid; i < e; i += 512) {
        unsigned int p = pairs[i];
        int d = p >> 24;
        int r = atomicAdd(&cur[d], 1);       // LDS
        col[s + sc[d] + r] = (int)(p & 0xFFFFFFu);
    }
}

// === prep: Wt bf16 transpose x3 + zero stats/bhist ==========================
__global__ void prep_k(const float* __restrict__ W0, const float* __restrict__ W1,
                       const float* __restrict__ W2,
                       unsigned short* __restrict__ T0, unsigned short* __restrict__ T1,
                       unsigned short* __restrict__ T2,
                       float* __restrict__ stats, int* __restrict__ bhist) {
    int y = blockIdx.y;
    int i = blockIdx.x * 256 + threadIdx.x;
    const float* W = (y == 0) ? W0 : (y == 1) ? W1 : W2;
    unsigned short* T = (y == 0) ? T0 : (y == 1) ? T1 : T2;
    if (i < 128 * 128) {
        int k = i >> 7, n = i & 127;
        T[n * 128 + k] = f2bf(W[k * 128 + n]);
    }
    if (y == 0) {
        if (i < 1024) stats[i] = 0.f;
        if (i < 512)  bhist[i] = 0;
    }
}

// ====== pad x [N,10] fp32 -> xp [N,16] bf16, full grid (1 elem/thread) ======
__global__ void padx_k(const float* __restrict__ X, unsigned short* __restrict__ XP, int N) {
    int i = blockIdx.x * 256 + threadIdx.x;
    if (i >= N * 16) return;
    int node = i >> 4, f = i & 15;
    XP[i] = (f < N_CLASS) ? f2bf(X[node * N_CLASS + f]) : (unsigned short)0;
}

// ==== layer-1 gather on bf16 padded rows (3.2MB -> per-XCD L2-resident) =====
__global__ void gather10_k(const unsigned short* __restrict__ XP, const int* __restrict__ col,
                           const int* __restrict__ rp, const int* __restrict__ cnt,
                           float* __restrict__ out, int N) {
    int t = blockIdx.x * 256 + threadIdx.x;
    int node = t >> 4, f = t & 15;
    if (node >= N) return;
    int start = rp[node], deg = cnt[node];
    float acc = bf2f(XP[node * 16 + f]);
    int j = 0;
    for (; j + 8 <= deg; j += 8) {
        int s0 = col[start + j],     s1 = col[start + j + 1];
        int s2 = col[start + j + 2], s3 = col[start + j + 3];
        int s4 = col[start + j + 4], s5 = col[start + j + 5];
        int s6 = col[start + j + 6], s7 = col[start + j + 7];
        float v0 = bf2f(XP[s0 * 16 + f]);
        float v1 = bf2f(XP[s1 * 16 + f]);
        float v2 = bf2f(XP[s2 * 16 + f]);
        float v3 = bf2f(XP[s3 * 16 + f]);
        float v4 = bf2f(XP[s4 * 16 + f]);
        float v5 = bf2f(XP[s5 * 16 + f]);
        float v6 = bf2f(XP[s6 * 16 + f]);
        float v7 = bf2f(XP[s7 * 16 + f]);
        acc += v0; acc += v1; acc += v2; acc += v3;
        acc += v4; acc += v5; acc += v6; acc += v7;
    }
    for (; j < deg; ++j)
        acc += bf2f(XP[col[start + j] * 16 + f]);
    out[node * 16 + f] = acc;
}

// ======= pre-activation: R = bnrelu(Z), once per node (N x 128 bf16) ========
__global__ __launch_bounds__(256) void act2_k(
    const unsigned short* __restrict__ Z, unsigned short* __restrict__ R,
    const float* __restrict__ st, const float* __restrict__ g,
    const float* __restrict__ b, int N, float inv_n) {
    __shared__ float sTab[128], hTab[128];
    int tid = threadIdx.x;
    if (tid < 128) {
        float m = st[tid] * inv_n;
        float v = fmaxf(st[128 + tid] * inv_n - m * m, 0.f);
        float s = g[tid] * rsqrtf(v + BN_EPS);
        sTab[tid] = s;
        hTab[tid] = b[tid] - m * s;
    }
    __syncthreads();
    int total = N * 16;                       // uint4 count
    for (int i = blockIdx.x * 256 + tid; i < total; i += gridDim.x * 256) {
        int k8 = (i & 15) * 8;
        uint4 v = ((const uint4*)Z)[i];
        unsigned short* us = (unsigned short*)&v;
#pragma unroll
        for (int j = 0; j < 8; ++j) {
            float f = fmaxf(fmaf(bf2f(us[j]), sTab[k8 + j], hTab[k8 + j]), 0.f);
            us[j] = f2bf(f);
        }
        ((uint4*)R)[i] = v;
    }
}

// == layer-2 gather: pure bf16 sum; scalarized CSR reads; 16 loads in flight =
__global__ __launch_bounds__(256) void gather_sum_k(
    const unsigned short* __restrict__ R, const int* __restrict__ col,
    const int* __restrict__ rp, const int* __restrict__ cnt,
    unsigned short* __restrict__ out, int N) {
    int wave = __builtin_amdgcn_readfirstlane((blockIdx.x * 256 + threadIdx.x) >> 6);
    int lane = threadIdx.x & 63;
    if (wave >= N) return;
    int start = __builtin_amdgcn_readfirstlane(rp[wave]);
    int deg   = __builtin_amdgcn_readfirstlane(cnt[wave]);
    const unsigned int* Xv = (const unsigned int*)R;   // 2 bf16 per uint
    unsigned int self = Xv[wave * 64 + lane];
    float a0 = lo_f(self);
    float a1 = hi_f(self);
    int j = 0;
    for (; j + 16 <= deg; j += 16) {
        int n0  = col[start + j],      n1  = col[start + j + 1];
        int n2  = col[start + j + 2],  n3  = col[start + j + 3];
        int n4  = col[start + j + 4],  n5  = col[start + j + 5];
        int n6  = col[start + j + 6],  n7  = col[start + j + 7];
        int n8  = col[start + j + 8],  n9  = col[start + j + 9];
        int n10 = col[start + j + 10], n11 = col[start + j + 11];
        int n12 = col[start + j + 12], n13 = col[start + j + 13];
        int n14 = col[start + j + 14], n15 = col[start + j + 15];
        unsigned int w0  = Xv[n0  * 64 + lane];
        unsigned int w1  = Xv[n1  * 64 + lane];
        unsigned int w2  = Xv[n2  * 64 + lane];
        unsigned int w3  = Xv[n3  * 64 + lane];
        unsigned int w4  = Xv[n4  * 64 + lane];
        unsigned int w5  = Xv[n5  * 64 + lane];
        unsigned int w6  = Xv[n6  * 64 + lane];
        unsigned int w7  = Xv[n7  * 64 + lane];
        unsigned int w8  = Xv[n8  * 64 + lane];
        unsigned int w9  = Xv[n9  * 64 + lane];
        unsigned int w10 = Xv[n10 * 64 + lane];
        unsigned int w11 = Xv[n11 * 64 + lane];
        unsigned int w12 = Xv[n12 * 64 + lane];
        unsigned int w13 = Xv[n13 * 64 + lane];
        unsigned int w14 = Xv[n14 * 64 + lane];
        unsigned int w15 = Xv[n15 * 64 + lane];
        a0 += lo_f(w0);  a1 += hi_f(w0);
        a0 += lo_f(w1);  a1 += hi_f(w1);
        a0 += lo_f(w2);  a1 += hi_f(w2);
        a0 += lo_f(w3);  a1 += hi_f(w3);
        a0 += lo_f(w4);  a1 += hi_f(w4);
        a0 += lo_f(w5);  a1 += hi_f(w5);
        a0 += lo_f(w6);  a1 += hi_f(w6);
        a0 += lo_f(w7);  a1 += hi_f(w7);
        a0 += lo_f(w8);  a1 += hi_f(w8);
        a0 += lo_f(w9);  a1 += hi_f(w9);
        a0 += lo_f(w10); a1 += hi_f(w10);
        a0 += lo_f(w11); a1 += hi_f(w11);
        a0 += lo_f(w12); a1 += hi_f(w12);
        a0 += lo_f(w13); a1 += hi_f(w13);
        a0 += lo_f(w14); a1 += hi_f(w14);
        a0 += lo_f(w15); a1 += hi_f(w15);
    }
    for (; j + 8 <= deg; j += 8) {
        int n0 = col[start + j],     n1 = col[start + j + 1];
        int n2 = col[start + j + 2], n3 = col[start + j + 3];
        int n4 = col[start + j + 4], n5 = col[start + j + 5];
        int n6 = col[start + j + 6], n7 = col[start + j + 7];
        unsigned int w0 = Xv[n0 * 64 + lane];
        unsigned int w1 = Xv[n1 * 64 + lane];
        unsigned int w2 = Xv[n2 * 64 + lane];
        unsigned int w3 = Xv[n3 * 64 + lane];
        unsigned int w4 = Xv[n4 * 64 + lane];
        unsigned int w5 = Xv[n5 * 64 + lane];
        unsigned int w6 = Xv[n6 * 64 + lane];
        unsigned int w7 = Xv[n7 * 64 + lane];
        a0 += lo_f(w0); a1 += hi_f(w0);
        a0 += lo_f(w1); a1 += hi_f(w1);
        a0 += lo_f(w2); a1 += hi_f(w2);
        a0 += lo_f(w3); a1 += hi_f(w3);
        a0 += lo_f(w4); a1 += hi_f(w4);
        a0 += lo_f(w5); a1 += hi_f(w5);
        a0 += lo_f(w6); a1 += hi_f(w6);
        a0 += lo_f(w7); a1 += hi_f(w7);
    }
    for (; j < deg; ++j) {
        unsigned int v = Xv[col[start + j] * 64 + lane];
        a0 += lo_f(v); a1 += hi_f(v);
    }
    unsigned int o = (unsigned int)f2bf(a0) | ((unsigned int)f2bf(a1) << 16);
    ((unsigned int*)out)[wave * 64 + lane] = o;
}

// == K=10 GEMM (padded [N,16] input) + bias + fp32 col-stats, bf16 output ====
__global__ __launch_bounds__(128) void gemm10_k(
    const float* __restrict__ A, const float* __restrict__ W,
    const float* __restrict__ bias, unsigned short* __restrict__ C,
    float* __restrict__ stOut, int N) {
    __shared__ float rb[16 * 16];
    const int tid = threadIdx.x;
    float wreg[N_CLASS];
#pragma unroll
    for (int k = 0; k < N_CLASS; ++k) wreg[k] = W[k * HIDDEN + tid];
    float bb = bias[tid];
    float s = 0.f, s2 = 0.f;
    for (int r0 = blockIdx.x * 16; r0 < N; r0 += gridDim.x * 16) {
        int nr = min(16, N - r0);
        for (int i = tid; i < nr * 16; i += 128) rb[i] = A[r0 * 16 + i];
        __syncthreads();
        for (int r = 0; r < nr; ++r) {
            float acc = bb;
#pragma unroll
            for (int k = 0; k < N_CLASS; ++k) acc = fmaf(rb[r * 16 + k], wreg[k], acc);
            C[(r0 + r) * HIDDEN + tid] = f2bf(acc);
            s += acc; s2 += acc * acc;
        }
        __syncthreads();
    }
    atomicAdd(stOut + tid, s);
    atomicAdd(stOut + HIDDEN + tid, s2);
}

// ============ MFMA bf16 GEMM: Zout = [bnrelu](Zin) @ W + bias ===============
template<bool BN>
__global__ __launch_bounds__(256, 3) void gemm_mfma_k(
    const unsigned short* __restrict__ Zin, const unsigned short* __restrict__ Wt,
    const float* __restrict__ bias,
    const float* __restrict__ stIn, const float* __restrict__ gIn,
    const float* __restrict__ tIn,
    unsigned short* __restrict__ Zout, float* __restrict__ stOut,
    int N, float inv_n) {
    __shared__ unsigned short Wl[128 * 136];    // 34816 B
    __shared__ unsigned short Al[64 * 136];     // 17408 B (C buffer + stats scratch)
    __shared__ float sTab[128], hTab[128], biasTab[128];   // 1536 B

    const int tid  = threadIdx.x;
    const int wv   = tid >> 6;
    const int ln   = tid & 63;
    const int half = ln >> 4;
    const int l16  = ln & 15;

    if (tid < 128) {
        biasTab[tid] = bias[tid];
        if (BN) {
            float m = stIn[tid] * inv_n;
            float v = fmaxf(stIn[128 + tid] * inv_n - m * m, 0.f);
            float s = gIn[tid] * rsqrtf(v + BN_EPS);
            sTab[tid] = s;
            hTab[tid] = tIn[tid] - m * s;
        }
    }
    for (int c = tid; c < 2048; c += 256) {
        int n = c >> 4, k8 = c & 15;
        uint4 v = *(const uint4*)(Wt + n * 128 + k8 * 8);
        *(uint4*)(&Wl[n * 136 + k8 * 8]) = v;
    }
    __syncthreads();

    float cs[8], cs2[8];
#pragma unroll
    for (int i = 0; i < 8; ++i) { cs[i] = 0.f; cs2[i] = 0.f; }

    const int ntiles = (N + 63) >> 6;
    for (int tile = blockIdx.x; tile < ntiles; tile += gridDim.x) {
        const int r0 = tile * 64;
        for (int c = tid; c < 1024; c += 256) {
            int r = c >> 4, k8 = c & 15;
            int gr = r0 + r; if (gr >= N) gr = N - 1;
            uint4 v = *(const uint4*)(Zin + gr * 128 + k8 * 8);
            if (BN) {
                unsigned short* us = (unsigned short*)&v;
                int kb = k8 * 8;
#pragma unroll
                for (int j = 0; j < 8; ++j) {
                    float f = fmaxf(fmaf(bf2f(us[j]), sTab[kb + j], hTab[kb + j]), 0.f);
                    us[j] = f2bf(f);
                }
            }
            *(uint4*)(&Al[r * 136 + k8 * 8]) = v;
        }
        __syncthreads();

        short8 afrag[4];
        const int arow = wv * 16 + l16;
#pragma unroll
        for (int s = 0; s < 4; ++s)
            afrag[s] = *(const short8*)(&Al[arow * 136 + s * 32 + half * 8]);
        __syncthreads();

#pragma unroll
        for (int ct = 0; ct < 8; ++ct) {
            floatx4 acc = {0.f, 0.f, 0.f, 0.f};
            const int bn_ = ct * 16 + l16;
#pragma unroll
            for (int s = 0; s < 4; ++s) {
                short8 bfrag = *(const short8*)(&Wl[bn_ * 136 + s * 32 + half * 8]);
                acc = __builtin_amdgcn_mfma_f32_16x16x32_bf16(afrag[s], bfrag, acc, 0, 0, 0);
            }
            float bcol = biasTab[bn_];
#pragma unroll
            for (int r = 0; r < 4; ++r) {
                int lrow = wv * 16 + half * 4 + r;
                float val = acc[r] + bcol;
                if (r0 + lrow < N) { cs[ct] += val; cs2[ct] += val * val; }
                Al[lrow * 136 + bn_] = f2bf(val);
            }
        }
        __syncthreads();

        for (int c = tid; c < 1024; c += 256) {
            int r = c >> 4, k8 = c & 15;
            int gr = r0 + r;
            if (gr < N)
                *(uint4*)(Zout + gr * 128 + k8 * 8) = *(const uint4*)(&Al[r * 136 + k8 * 8]);
        }
        __syncthreads();
    }

    // stats reduction in Al-aliased scratch (Al dead after last writeback+sync)
    float* red = (float*)Al;                   // [0..127]=sum, [128..255]=sumsq
    if (tid < 256) red[tid] = 0.f;
    __syncthreads();
#pragma unroll
    for (int ct = 0; ct < 8; ++ct) {
        float a = cs[ct], b = cs2[ct];
        a += __shfl_xor(a, 16); a += __shfl_xor(a, 32);
        b += __shfl_xor(b, 16); b += __shfl_xor(b, 32);
        if (half == 0) {
            atomicAdd(&red[ct * 16 + l16], a);
            atomicAdd(&red[128 + ct * 16 + l16], b);
        }
    }
    __syncthreads();
    if (tid < 128) {
        atomicAdd(stOut + tid, red[tid]);
        atomicAdd(stOut + 128 + tid, red[128 + tid]);
    }
}

// ==== final: BN+ReLU -> @wf + bf -> log_softmax, MFMA (wf padded 10->16) ====
__global__ __launch_bounds__(256) void final_mfma_k(
    const unsigned short* __restrict__ Z, const float* __restrict__ st,
    const float* __restrict__ g, const float* __restrict__ b,
    const float* __restrict__ wf, const float* __restrict__ bfc,
    float* __restrict__ out, int N, float inv_n) {
    __shared__ unsigned short Al[64 * 136];     // 17.4 KB
    __shared__ unsigned short Bl[16 * 136];     // 4.4 KB
    __shared__ float sTab[128], hTab[128], biasTab[16];

    const int tid  = threadIdx.x;
    const int wv   = tid >> 6;
    const int ln   = tid & 63;
    const int half = ln >> 4;
    const int l16  = ln & 15;

    if (tid < 128) {
        float m = st[tid] * inv_n;
        float v = fmaxf(st[128 + tid] * inv_n - m * m, 0.f);
        float s = g[tid] * rsqrtf(v + BN_EPS);
        sTab[tid] = s;
        hTab[tid] = b[tid] - m * s;
    }
    if (tid < 16) biasTab[tid] = (tid < N_CLASS) ? bfc[tid] : -3.0e38f;
    {   // Bl[n][k] = f2bf(wf[k][n]) for n<10, else 0;  16 rows x 128 k
        int n = tid >> 4, k8 = (tid & 15) * 8;
        uint4 v;
        unsigned short* us = (unsigned short*)&v;
#pragma unroll
        for (int j = 0; j < 8; ++j)
            us[j] = (n < N_CLASS) ? f2bf(wf[(k8 + j) * N_CLASS + n]) : (unsigned short)0;
        *(uint4*)(&Bl[n * 136 + k8]) = v;
    }
    __syncthreads();

    short8 bfrag[4];
#pragma unroll
    for (int s = 0; s < 4; ++s)
        bfrag[s] = *(const short8*)(&Bl[l16 * 136 + s * 32 + half * 8]);

    const int ntiles = (N + 63) >> 6;
    for (int tile = blockIdx.x; tile < ntiles; tile += gridDim.x) {
        const int r0 = tile * 64;
        for (int c = tid; c < 1024; c += 256) {
            int r = c >> 4, k8 = c & 15;
            int gr = r0 + r; if (gr >= N) gr = N - 1;
            uint4 v = *(const uint4*)(Z + gr * 128 + k8 * 8);
            unsigned short* us = (unsigned short*)&v;
            int kb = k8 * 8;
#pragma unroll
            for (int j = 0; j < 8; ++j) {
                float f = fmaxf(fmaf(bf2f(us[j]), sTab[kb + j], hTab[kb + j]), 0.f);
                us[j] = f2bf(f);
            }
            *(uint4*)(&Al[r * 136 + k8 * 8]) = v;
        }
        __syncthreads();

        short8 afrag[4];
        const int arow = wv * 16 + l16;
#pragma unroll
        for (int s = 0; s < 4; ++s)
            afrag[s] = *(const short8*)(&Al[arow * 136 + s * 32 + half * 8]);
        __syncthreads();    // Al free for next tile's staging

        floatx4 acc = {0.f, 0.f, 0.f, 0.f};
#pragma unroll
        for (int s = 0; s < 4; ++s)
            acc = __builtin_amdgcn_mfma_f32_16x16x32_bf16(afrag[s], bfrag[s], acc, 0, 0, 0);

        float bcol = biasTab[l16];
#pragma unroll
        for (int r = 0; r < 4; ++r) {
            float lg = acc[r] + bcol;                 // -3e38 for pad cols
            float mx = lg;
            mx = fmaxf(mx, __shfl_xor(mx, 1));
            mx = fmaxf(mx, __shfl_xor(mx, 2));
            mx = fmaxf(mx, __shfl_xor(mx, 4));
            mx = fmaxf(mx, __shfl_xor(mx, 8));
            float p = __expf(lg - mx);                // pad cols -> 0
            float se = p;
            se += __shfl_xor(se, 1);
            se += __shfl_xor(se, 2);
            se += __shfl_xor(se, 4);
            se += __shfl_xor(se, 8);
            float ls = __logf(se);
            int grow = r0 + wv * 16 + half * 4 + r;
            if (l16 < N_CLASS && grow < N)
                out[grow * N_CLASS + l16] = lg - mx - ls;
        }
    }
}

// ===========================================================================

extern "C" void kernel_launch(void* const* d_in, const int* in_sizes, int n_in,
                              void* d_out, int out_size, void* d_ws, size_t ws_size,
                              hipStream_t stream) {
    const float* x   = (const float*)d_in[0];
    const float* w11 = (const float*)d_in[2];
    const float* b11 = (const float*)d_in[3];
    const float* g11 = (const float*)d_in[4];
    const float* t11 = (const float*)d_in[5];
    const float* w12 = (const float*)d_in[6];
    const float* b12 = (const float*)d_in[7];
    const float* g12 = (const float*)d_in[8];
    const float* t12 = (const float*)d_in[9];
    const float* w21 = (const float*)d_in[10];
    const float* b21 = (const float*)d_in[11];
    const float* g21 = (const float*)d_in[12];
    const float* t21 = (const float*)d_in[13];
    const float* w22 = (const float*)d_in[14];
    const float* b22 = (const float*)d_in[15];
    const float* g22 = (const float*)d_in[16];
    const float* t22 = (const float*)d_in[17];
    const float* wf  = (const float*)d_in[18];
    const float* bf  = (const float*)d_in[19];
    const int*   ei  = (const int*)d_in[20];

    const int N = in_sizes[0] / N_CLASS;      // 100000
    const int E = in_sizes[1];                // 1600000
    const float inv_n = 1.0f / (float)N;
    const int NBK = (N + 255) >> 8;           // 391 buckets (<= 512)

    // ---- workspace layout (16B-aligned sections) ----
    char* base = (char*)d_ws;
    size_t off = 0;
    auto take = [&](size_t bytes) { void* p = base + off; off += (bytes + 15) & ~(size_t)15; return p; };
    float*          stats   = (float*)take(1024 * 4);
    unsigned short* xp      = (unsigned short*)take((size_t)N * 16 * 2);
    float*          h0      = (float*)take((size_t)N * 16 * 4);
    int*            cnt     = (int*)take((size_t)N * 4);
    int*            row_ptr = (int*)take((size_t)N * 4);
    int*            bhist   = (int*)take(512 * 4);
    int*            bstart  = (int*)take(520 * 4);
    int*            bbase   = (int*)take(512 * 256 * 4);   // [bucket][block]
    unsigned int*   pairs   = (unsigned int*)take((size_t)E * 4);
    int*            col     = (int*)take((size_t)E * 4);
    unsigned short* bufA    = (unsigned short*)take((size_t)N * HIDDEN * 2);
    unsigned short* bufB    = (unsigned short*)take((size_t)N * HIDDEN * 2);
    unsigned short* bufC    = (unsigned short*)take((size_t)N * HIDDEN * 2);
    unsigned short* Wt1     = (unsigned short*)take(128 * 128 * 2);
    unsigned short* Wt2     = (unsigned short*)take(128 * 128 * 2);
    unsigned short* Wt3     = (unsigned short*)take(128 * 128 * 2);

    // ---- prep: weights->bf16^T + zero stats/bhist; padx at full grid ----
    prep_k<<<dim3(64, 3), 256, 0, stream>>>(w12, w21, w22, Wt1, Wt2, Wt3,
                                            stats, bhist);
    padx_k<<<(N * 16 + 255) / 256, 256, 0, stream>>>(x, xp, N);

    // ---- bucketed CSR build (atomic-free scatter via per-block histograms) --
    bhist_k<<<256, 512, 0, stream>>>(ei, bhist, bbase, E);
    bscan_k<<<1, 512, 0, stream>>>(bhist, bstart, NBK);
    bscan2_k<<<NBK, 256, 0, stream>>>(bbase, bstart);
    bscatter_k<<<256, 512, 0, stream>>>(ei, bbase, pairs, E);
    bcsr_k<<<NBK, 512, 0, stream>>>(pairs, bstart, row_ptr, cnt, col, N);

    // ---- layer 1 ----
    gather10_k<<<(N * 16 + 255) / 256, 256, 0, stream>>>(xp, col, row_ptr, cnt, h0, N);
    gemm10_k<<<512, 128, 0, stream>>>(h0, w11, b11, bufA, stats, N);            // Z1 + stats0
    gemm_mfma_k<true><<<768, 256, 0, stream>>>(bufA, Wt1, b12, stats, g11, t11,
                                               bufB, stats + 256, N, inv_n);    // Z2 + stats1

    // ---- layer 2 aggregation: activate once per node, then pure-sum gather --
    act2_k<<<3125, 256, 0, stream>>>(bufB, bufC, stats + 256, g12, t12, N, inv_n);
    gather_sum_k<<<(N * 64 + 255) / 256, 256, 0, stream>>>(bufC, col, row_ptr, cnt,
                                                           bufA, N);

    // ---- layer 2 MLP ----
    gemm_mfma_k<false><<<768, 256, 0, stream>>>(bufA, Wt2, b21, nullptr, nullptr, nullptr,
                                                bufB, stats + 512, N, inv_n);   // Z3 + stats2
    gemm_mfma_k<true><<<768, 256, 0, stream>>>(bufB, Wt3, b22, stats + 512, g21, t21,
                                               bufA, stats + 768, N, inv_n);    // Z4 + stats3

    // ---- final linear + log_softmax (BN4+ReLU fused, MFMA) ----
    final_mfma_k<<<782, 256, 0, stream>>>(bufA, stats + 768, g22, t22,
                                          wf, bf, (float*)d_out, N, inv_n);
}

// Round 13
// 376.758 us; speedup vs baseline: 1.1700x; 1.0641x over previous
//
#include <hip/hip_runtime.h>

#define N_CLASS 10
#define HIDDEN 128
#define BN_EPS 1e-5f

typedef short short8 __attribute__((ext_vector_type(8)));   // 8 bf16 in 4 VGPRs
typedef float floatx4 __attribute__((ext_vector_type(4)));

__device__ __forceinline__ float bf2f(unsigned short u) {
    unsigned int x = ((unsigned int)u) << 16;
    float f; __builtin_memcpy(&f, &x, 4); return f;
}
__device__ __forceinline__ unsigned short f2bf(float f) {
    unsigned int x; __builtin_memcpy(&x, &f, 4);
    x += 0x7FFFu + ((x >> 16) & 1u);          // round-to-nearest-even
    return (unsigned short)(x >> 16);
}
// exact bf16 unpack of a packed uint, 1 VALU op each
__device__ __forceinline__ float lo_f(unsigned int u) {
    unsigned int x = u << 16; float f; __builtin_memcpy(&f, &x, 4); return f;
}
__device__ __forceinline__ float hi_f(unsigned int u) {
    unsigned int x = u & 0xffff0000u; float f; __builtin_memcpy(&f, &x, 4); return f;
}

// ================= bucketed CSR build (no per-edge global atomics) ==========
// bucket = dst >> 8  (256 dsts per bucket; NBK = ceil(N/256) = 391 <= 512)
// pairs entry packed: src (low 24 bits, src < 2^17) | dst&255 (high 8 bits)
// bhist & bscatter use IDENTICAL chunked edge partitions (grid 256) so the
// per-block histograms in bbase[bucket][block] give exact placement bases.

__global__ __launch_bounds__(512) void bhist_k(const int* __restrict__ ei,
                                               int* __restrict__ bhist,
                                               int* __restrict__ bbase, int E) {
    __shared__ int h[512];
    int tid = threadIdx.x;
    h[tid] = 0;
    __syncthreads();
    int chunk = (E + gridDim.x - 1) / gridDim.x;
    int e0 = blockIdx.x * chunk;
    int e1 = min(e0 + chunk, E);
    for (int e = e0 + tid; e < e1; e += 512)
        atomicAdd(&h[((unsigned)ei[E + e]) >> 8], 1);
    __syncthreads();
    bbase[tid * 256 + blockIdx.x] = h[tid];           // [bucket][block]
    if (h[tid]) atomicAdd(&bhist[tid], h[tid]);
}

__global__ __launch_bounds__(512) void bscan_k(const int* __restrict__ bhist,
                                               int* __restrict__ bstart, int NBK) {
    __shared__ int sm[512];
    int t = threadIdx.x;
    sm[t] = (t < NBK) ? bhist[t] : 0;
    __syncthreads();
    for (int off = 1; off < 512; off <<= 1) {
        int u = (t >= off) ? sm[t - off] : 0;
        __syncthreads();
        sm[t] += u;
        __syncthreads();
    }
    bstart[t] = (t == 0) ? 0 : sm[t - 1];             // all 512 written
    if (t == 0) bstart[512] = sm[511];
}

// per-bucket exclusive scan of the 256 per-block counts, + bucket base
__global__ __launch_bounds__(256) void bscan2_k(int* __restrict__ bbase,
                                                const int* __restrict__ bstart) {
    __shared__ int sm[256];
    int b = blockIdx.x;            // bucket
    int t = threadIdx.x;           // edge-chunk block index
    int v = bbase[b * 256 + t];
    sm[t] = v;
    __syncthreads();
    for (int off = 1; off < 256; off <<= 1) {
        int u = (t >= off) ? sm[t - off] : 0;
        __syncthreads();
        sm[t] += u;
        __syncthreads();
    }
    bbase[b * 256 + t] = bstart[b] + sm[t] - v;       // exclusive
}

__global__ __launch_bounds__(512) void bscatter_k(const int* __restrict__ ei,
                                                  const int* __restrict__ bbase,
                                                  unsigned int* __restrict__ pairs, int E) {
    __shared__ int base[512], cur[512];
    int tid = threadIdx.x;
    base[tid] = bbase[tid * 256 + blockIdx.x];
    cur[tid] = 0;
    __syncthreads();
    int chunk = (E + gridDim.x - 1) / gridDim.x;
    int e0 = blockIdx.x * chunk;
    int e1 = min(e0 + chunk, E);
    for (int e = e0 + tid; e < e1; e += 512) {
        unsigned int s = (unsigned int)ei[e];
        unsigned int d = (unsigned int)ei[E + e];
        int bk = d >> 8;
        int r = atomicAdd(&cur[bk], 1);      // LDS only
        pairs[base[bk] + r] = s | ((d & 255u) << 24);
    }
}

__global__ __launch_bounds__(512) void bcsr_k(const unsigned int* __restrict__ pairs,
                                              const int* __restrict__ bstart,
                                              int* __restrict__ row_ptr,
                                              int* __restrict__ cnt,
                                              int* __restrict__ col, int N) {
    __shared__ int h[256], sc[256], cur[256];
    int tid = threadIdx.x;
    if (tid < 256) { h[tid] = 0; cur[tid] = 0; }
    __syncthreads();
    int b = blockIdx.x, lo = b << 8;
    int s = bstart[b], e = bstart[b + 1];
    for (int i = s + tid; i < e; i += 512)
        atomicAdd(&h[pairs[i] >> 24], 1);    // LDS
    __syncthreads();
    if (tid < 256) sc[tid] = h[tid];
    __syncthreads();
    for (int off = 1; off < 256; off <<= 1) {
        int u = (tid < 256 && tid >= off) ? sc[tid - off] : 0;
        __syncthreads();
        if (tid < 256) sc[tid] += u;
        __syncthreads();
    }
    if (tid < 256) {
        int d = lo + tid;
        if (d < N) { cnt[d] = h[tid]; row_ptr[d] = s + sc[tid] - h[tid]; }
        sc[tid] -= h[tid];                   // exclusive, for the fill below
    }
    __syncthreads();
    for (int i = s + tid; i < e; i += 512) {
        unsigned int p = pairs[i];
        int d = p >> 24;
        int r = atomicAdd(&cur[d], 1);       // LDS
        col[s + sc[d] + r] = (int)(p & 0xFFFFFFu);
    }
}

// === prep: Wt bf16 transpose x3 + zero stats/bhist ==========================
__global__ void prep_k(const float* __restrict__ W0, const float* __restrict__ W1,
                       const float* __restrict__ W2,
                       unsigned short* __restrict__ T0, unsigned short* __restrict__ T1,
                       unsigned short* __restrict__ T2,
                       float* __restrict__ stats, int* __restrict__ bhist) {
    int y = blockIdx.y;
    int i = blockIdx.x * 256 + threadIdx.x;
    const float* W = (y == 0) ? W0 : (y == 1) ? W1 : W2;
    unsigned short* T = (y == 0) ? T0 : (y == 1) ? T1 : T2;
    if (i < 128 * 128) {
        int k = i >> 7, n = i & 127;
        T[n * 128 + k] = f2bf(W[k * 128 + n]);
    }
    if (y == 0) {
        if (i < 1024) stats[i] = 0.f;
        if (i < 512)  bhist[i] = 0;
    }
}

// ====== pad x [N,10] fp32 -> xp [N,16] bf16, full grid (1 elem/thread) ======
__global__ void padx_k(const float* __restrict__ X, unsigned short* __restrict__ XP, int N) {
    int i = blockIdx.x * 256 + threadIdx.x;
    if (i >= N * 16) return;
    int node = i >> 4, f = i & 15;
    XP[i] = (f < N_CLASS) ? f2bf(X[node * N_CLASS + f]) : (unsigned short)0;
}

// ==== layer-1 gather on bf16 padded rows (3.2MB -> per-XCD L2-resident) =====
__global__ void gather10_k(const unsigned short* __restrict__ XP, const int* __restrict__ col,
                           const int* __restrict__ rp, const int* __restrict__ cnt,
                           float* __restrict__ out, int N) {
    int t = blockIdx.x * 256 + threadIdx.x;
    int node = t >> 4, f = t & 15;
    if (node >= N) return;
    int start = rp[node], deg = cnt[node];
    float acc = bf2f(XP[node * 16 + f]);
    int j = 0;
    for (; j + 8 <= deg; j += 8) {
        int s0 = col[start + j],     s1 = col[start + j + 1];
        int s2 = col[start + j + 2], s3 = col[start + j + 3];
        int s4 = col[start + j + 4], s5 = col[start + j + 5];
        int s6 = col[start + j + 6], s7 = col[start + j + 7];
        float v0 = bf2f(XP[s0 * 16 + f]);
        float v1 = bf2f(XP[s1 * 16 + f]);
        float v2 = bf2f(XP[s2 * 16 + f]);
        float v3 = bf2f(XP[s3 * 16 + f]);
        float v4 = bf2f(XP[s4 * 16 + f]);
        float v5 = bf2f(XP[s5 * 16 + f]);
        float v6 = bf2f(XP[s6 * 16 + f]);
        float v7 = bf2f(XP[s7 * 16 + f]);
        acc += v0; acc += v1; acc += v2; acc += v3;
        acc += v4; acc += v5; acc += v6; acc += v7;
    }
    for (; j < deg; ++j)
        acc += bf2f(XP[col[start + j] * 16 + f]);
    out[node * 16 + f] = acc;
}

// ======= pre-activation: R = bnrelu(Z), once per node (N x 128 bf16) ========
__global__ __launch_bounds__(256) void act2_k(
    const unsigned short* __restrict__ Z, unsigned short* __restrict__ R,
    const float* __restrict__ st, const float* __restrict__ g,
    const float* __restrict__ b, int N, float inv_n) {
    __shared__ float sTab[128], hTab[128];
    int tid = threadIdx.x;
    if (tid < 128) {
        float m = st[tid] * inv_n;
        float v = fmaxf(st[128 + tid] * inv_n - m * m, 0.f);
        float s = g[tid] * rsqrtf(v + BN_EPS);
        sTab[tid] = s;
        hTab[tid] = b[tid] - m * s;
    }
    __syncthreads();
    int total = N * 16;                       // uint4 count
    for (int i = blockIdx.x * 256 + tid; i < total; i += gridDim.x * 256) {
        int k8 = (i & 15) * 8;
        uint4 v = ((const uint4*)Z)[i];
        unsigned short* us = (unsigned short*)&v;
#pragma unroll
        for (int j = 0; j < 8; ++j) {
            float f = fmaxf(fmaf(bf2f(us[j]), sTab[k8 + j], hTab[k8 + j]), 0.f);
            us[j] = f2bf(f);
        }
        ((uint4*)R)[i] = v;
    }
}

// == layer-2 gather: pure bf16 sum; scalarized CSR reads; 16 loads in flight =
__global__ __launch_bounds__(256) void gather_sum_k(
    const unsigned short* __restrict__ R, const int* __restrict__ col,
    const int* __restrict__ rp, const int* __restrict__ cnt,
    unsigned short* __restrict__ out, int N) {
    int wave = __builtin_amdgcn_readfirstlane((blockIdx.x * 256 + threadIdx.x) >> 6);
    int lane = threadIdx.x & 63;
    if (wave >= N) return;
    int start = __builtin_amdgcn_readfirstlane(rp[wave]);
    int deg   = __builtin_amdgcn_readfirstlane(cnt[wave]);
    const unsigned int* Xv = (const unsigned int*)R;   // 2 bf16 per uint
    unsigned int self = Xv[wave * 64 + lane];
    float a0 = lo_f(self);
    float a1 = hi_f(self);
    int j = 0;
    for (; j + 16 <= deg; j += 16) {
        int n0  = col[start + j],      n1  = col[start + j + 1];
        int n2  = col[start + j + 2],  n3  = col[start + j + 3];
        int n4  = col[start + j + 4],  n5  = col[start + j + 5];
        int n6  = col[start + j + 6],  n7  = col[start + j + 7];
        int n8  = col[start + j + 8],  n9  = col[start + j + 9];
        int n10 = col[start + j + 10], n11 = col[start + j + 11];
        int n12 = col[start + j + 12], n13 = col[start + j + 13];
        int n14 = col[start + j + 14], n15 = col[start + j + 15];
        unsigned int w0  = Xv[n0  * 64 + lane];
        unsigned int w1  = Xv[n1  * 64 + lane];
        unsigned int w2  = Xv[n2  * 64 + lane];
        unsigned int w3  = Xv[n3  * 64 + lane];
        unsigned int w4  = Xv[n4  * 64 + lane];
        unsigned int w5  = Xv[n5  * 64 + lane];
        unsigned int w6  = Xv[n6  * 64 + lane];
        unsigned int w7  = Xv[n7  * 64 + lane];
        unsigned int w8  = Xv[n8  * 64 + lane];
        unsigned int w9  = Xv[n9  * 64 + lane];
        unsigned int w10 = Xv[n10 * 64 + lane];
        unsigned int w11 = Xv[n11 * 64 + lane];
        unsigned int w12 = Xv[n12 * 64 + lane];
        unsigned int w13 = Xv[n13 * 64 + lane];
        unsigned int w14 = Xv[n14 * 64 + lane];
        unsigned int w15 = Xv[n15 * 64 + lane];
        a0 += lo_f(w0);  a1 += hi_f(w0);
        a0 += lo_f(w1);  a1 += hi_f(w1);
        a0 += lo_f(w2);  a1 += hi_f(w2);
        a0 += lo_f(w3);  a1 += hi_f(w3);
        a0 += lo_f(w4);  a1 += hi_f(w4);
        a0 += lo_f(w5);  a1 += hi_f(w5);
        a0 += lo_f(w6);  a1 += hi_f(w6);
        a0 += lo_f(w7);  a1 += hi_f(w7);
        a0 += lo_f(w8);  a1 += hi_f(w8);
        a0 += lo_f(w9);  a1 += hi_f(w9);
        a0 += lo_f(w10); a1 += hi_f(w10);
        a0 += lo_f(w11); a1 += hi_f(w11);
        a0 += lo_f(w12); a1 += hi_f(w12);
        a0 += lo_f(w13); a1 += hi_f(w13);
        a0 += lo_f(w14); a1 += hi_f(w14);
        a0 += lo_f(w15); a1 += hi_f(w15);
    }
    for (; j + 8 <= deg; j += 8) {
        int n0 = col[start + j],     n1 = col[start + j + 1];
        int n2 = col[start + j + 2], n3 = col[start + j + 3];
        int n4 = col[start + j + 4], n5 = col[start + j + 5];
        int n6 = col[start + j + 6], n7 = col[start + j + 7];
        unsigned int w0 = Xv[n0 * 64 + lane];
        unsigned int w1 = Xv[n1 * 64 + lane];
        unsigned int w2 = Xv[n2 * 64 + lane];
        unsigned int w3 = Xv[n3 * 64 + lane];
        unsigned int w4 = Xv[n4 * 64 + lane];
        unsigned int w5 = Xv[n5 * 64 + lane];
        unsigned int w6 = Xv[n6 * 64 + lane];
        unsigned int w7 = Xv[n7 * 64 + lane];
        a0 += lo_f(w0); a1 += hi_f(w0);
        a0 += lo_f(w1); a1 += hi_f(w1);
        a0 += lo_f(w2); a1 += hi_f(w2);
        a0 += lo_f(w3); a1 += hi_f(w3);
        a0 += lo_f(w4); a1 += hi_f(w4);
        a0 += lo_f(w5); a1 += hi_f(w5);
        a0 += lo_f(w6); a1 += hi_f(w6);
        a0 += lo_f(w7); a1 += hi_f(w7);
    }
    for (; j < deg; ++j) {
        unsigned int v = Xv[col[start + j] * 64 + lane];
        a0 += lo_f(v); a1 += hi_f(v);
    }
    unsigned int o = (unsigned int)f2bf(a0) | ((unsigned int)f2bf(a1) << 16);
    ((unsigned int*)out)[wave * 64 + lane] = o;
}

// == K=10 GEMM (padded [N,16] input) + bias + fp32 col-stats, bf16 output ====
__global__ __launch_bounds__(128) void gemm10_k(
    const float* __restrict__ A, const float* __restrict__ W,
    const float* __restrict__ bias, unsigned short* __restrict__ C,
    float* __restrict__ stOut, int N) {
    __shared__ float rb[16 * 16];
    const int tid = threadIdx.x;
    float wreg[N_CLASS];
#pragma unroll
    for (int k = 0; k < N_CLASS; ++k) wreg[k] = W[k * HIDDEN + tid];
    float bb = bias[tid];
    float s = 0.f, s2 = 0.f;
    for (int r0 = blockIdx.x * 16; r0 < N; r0 += gridDim.x * 16) {
        int nr = min(16, N - r0);
        for (int i = tid; i < nr * 16; i += 128) rb[i] = A[r0 * 16 + i];
        __syncthreads();
        for (int r = 0; r < nr; ++r) {
            float acc = bb;
#pragma unroll
            for (int k = 0; k < N_CLASS; ++k) acc = fmaf(rb[r * 16 + k], wreg[k], acc);
            C[(r0 + r) * HIDDEN + tid] = f2bf(acc);
            s += acc; s2 += acc * acc;
        }
        __syncthreads();
    }
    atomicAdd(stOut + tid, s);
    atomicAdd(stOut + HIDDEN + tid, s2);
}

// ============ MFMA bf16 GEMM: Zout = [bnrelu](Zin) @ W + bias ===============
template<bool BN>
__global__ __launch_bounds__(256, 3) void gemm_mfma_k(
    const unsigned short* __restrict__ Zin, const unsigned short* __restrict__ Wt,
    const float* __restrict__ bias,
    const float* __restrict__ stIn, const float* __restrict__ gIn,
    const float* __restrict__ tIn,
    unsigned short* __restrict__ Zout, float* __restrict__ stOut,
    int N, float inv_n) {
    __shared__ unsigned short Wl[128 * 136];    // 34816 B
    __shared__ unsigned short Al[64 * 136];     // 17408 B (C buffer + stats scratch)
    __shared__ float sTab[128], hTab[128], biasTab[128];   // 1536 B

    const int tid  = threadIdx.x;
    const int wv   = tid >> 6;
    const int ln   = tid & 63;
    const int half = ln >> 4;
    const int l16  = ln & 15;

    if (tid < 128) {
        biasTab[tid] = bias[tid];
        if (BN) {
            float m = stIn[tid] * inv_n;
            float v = fmaxf(stIn[128 + tid] * inv_n - m * m, 0.f);
            float s = gIn[tid] * rsqrtf(v + BN_EPS);
            sTab[tid] = s;
            hTab[tid] = tIn[tid] - m * s;
        }
    }
    for (int c = tid; c < 2048; c += 256) {
        int n = c >> 4, k8 = c & 15;
        uint4 v = *(const uint4*)(Wt + n * 128 + k8 * 8);
        *(uint4*)(&Wl[n * 136 + k8 * 8]) = v;
    }
    __syncthreads();

    float cs[8], cs2[8];
#pragma unroll
    for (int i = 0; i < 8; ++i) { cs[i] = 0.f; cs2[i] = 0.f; }

    const int ntiles = (N + 63) >> 6;
    for (int tile = blockIdx.x; tile < ntiles; tile += gridDim.x) {
        const int r0 = tile * 64;
        for (int c = tid; c < 1024; c += 256) {
            int r = c >> 4, k8 = c & 15;
            int gr = r0 + r; if (gr >= N) gr = N - 1;
            uint4 v = *(const uint4*)(Zin + gr * 128 + k8 * 8);
            if (BN) {
                unsigned short* us = (unsigned short*)&v;
                int kb = k8 * 8;
#pragma unroll
                for (int j = 0; j < 8; ++j) {
                    float f = fmaxf(fmaf(bf2f(us[j]), sTab[kb + j], hTab[kb + j]), 0.f);
                    us[j] = f2bf(f);
                }
            }
            *(uint4*)(&Al[r * 136 + k8 * 8]) = v;
        }
        __syncthreads();

        short8 afrag[4];
        const int arow = wv * 16 + l16;
#pragma unroll
        for (int s = 0; s < 4; ++s)
            afrag[s] = *(const short8*)(&Al[arow * 136 + s * 32 + half * 8]);
        __syncthreads();

#pragma unroll
        for (int ct = 0; ct < 8; ++ct) {
            floatx4 acc = {0.f, 0.f, 0.f, 0.f};
            const int bn_ = ct * 16 + l16;
#pragma unroll
            for (int s = 0; s < 4; ++s) {
                short8 bfrag = *(const short8*)(&Wl[bn_ * 136 + s * 32 + half * 8]);
                acc = __builtin_amdgcn_mfma_f32_16x16x32_bf16(afrag[s], bfrag, acc, 0, 0, 0);
            }
            float bcol = biasTab[bn_];
#pragma unroll
            for (int r = 0; r < 4; ++r) {
                int lrow = wv * 16 + half * 4 + r;
                float val = acc[r] + bcol;
                if (r0 + lrow < N) { cs[ct] += val; cs2[ct] += val * val; }
                Al[lrow * 136 + bn_] = f2bf(val);
            }
        }
        __syncthreads();

        for (int c = tid; c < 1024; c += 256) {
            int r = c >> 4, k8 = c & 15;
            int gr = r0 + r;
            if (gr < N)
                *(uint4*)(Zout + gr * 128 + k8 * 8) = *(const uint4*)(&Al[r * 136 + k8 * 8]);
        }
        __syncthreads();
    }

    // stats reduction in Al-aliased scratch (Al dead after last writeback+sync)
    float* red = (float*)Al;                   // [0..127]=sum, [128..255]=sumsq
    if (tid < 256) red[tid] = 0.f;
    __syncthreads();
#pragma unroll
    for (int ct = 0; ct < 8; ++ct) {
        float a = cs[ct], b = cs2[ct];
        a += __shfl_xor(a, 16); a += __shfl_xor(a, 32);
        b += __shfl_xor(b, 16); b += __shfl_xor(b, 32);
        if (half == 0) {
            atomicAdd(&red[ct * 16 + l16], a);
            atomicAdd(&red[128 + ct * 16 + l16], b);
        }
    }
    __syncthreads();
    if (tid < 128) {
        atomicAdd(stOut + tid, red[tid]);
        atomicAdd(stOut + 128 + tid, red[128 + tid]);
    }
}

// ==== final: BN+ReLU -> @wf + bf -> log_softmax, MFMA (wf padded 10->16) ====
__global__ __launch_bounds__(256) void final_mfma_k(
    const unsigned short* __restrict__ Z, const float* __restrict__ st,
    const float* __restrict__ g, const float* __restrict__ b,
    const float* __restrict__ wf, const float* __restrict__ bfc,
    float* __restrict__ out, int N, float inv_n) {
    __shared__ unsigned short Al[64 * 136];     // 17.4 KB
    __shared__ unsigned short Bl[16 * 136];     // 4.4 KB
    __shared__ float sTab[128], hTab[128], biasTab[16];

    const int tid  = threadIdx.x;
    const int wv   = tid >> 6;
    const int ln   = tid & 63;
    const int half = ln >> 4;
    const int l16  = ln & 15;

    if (tid < 128) {
        float m = st[tid] * inv_n;
        float v = fmaxf(st[128 + tid] * inv_n - m * m, 0.f);
        float s = g[tid] * rsqrtf(v + BN_EPS);
        sTab[tid] = s;
        hTab[tid] = b[tid] - m * s;
    }
    if (tid < 16) biasTab[tid] = (tid < N_CLASS) ? bfc[tid] : -3.0e38f;
    {   // Bl[n][k] = f2bf(wf[k][n]) for n<10, else 0;  16 rows x 128 k
        int n = tid >> 4, k8 = (tid & 15) * 8;
        uint4 v;
        unsigned short* us = (unsigned short*)&v;
#pragma unroll
        for (int j = 0; j < 8; ++j)
            us[j] = (n < N_CLASS) ? f2bf(wf[(k8 + j) * N_CLASS + n]) : (unsigned short)0;
        *(uint4*)(&Bl[n * 136 + k8]) = v;
    }
    __syncthreads();

    short8 bfrag[4];
#pragma unroll
    for (int s = 0; s < 4; ++s)
        bfrag[s] = *(const short8*)(&Bl[l16 * 136 + s * 32 + half * 8]);

    const int ntiles = (N + 63) >> 6;
    for (int tile = blockIdx.x; tile < ntiles; tile += gridDim.x) {
        const int r0 = tile * 64;
        for (int c = tid; c < 1024; c += 256) {
            int r = c >> 4, k8 = c & 15;
            int gr = r0 + r; if (gr >= N) gr = N - 1;
            uint4 v = *(const uint4*)(Z + gr * 128 + k8 * 8);
            unsigned short* us = (unsigned short*)&v;
            int kb = k8 * 8;
#pragma unroll
            for (int j = 0; j < 8; ++j) {
                float f = fmaxf(fmaf(bf2f(us[j]), sTab[kb + j], hTab[kb + j]), 0.f);
                us[j] = f2bf(f);
            }
            *(uint4*)(&Al[r * 136 + k8 * 8]) = v;
        }
        __syncthreads();

        short8 afrag[4];
        const int arow = wv * 16 + l16;
#pragma unroll
        for (int s = 0; s < 4; ++s)
            afrag[s] = *(const short8*)(&Al[arow * 136 + s * 32 + half * 8]);
        __syncthreads();    // Al free for next tile's staging

        floatx4 acc = {0.f, 0.f, 0.f, 0.f};
#pragma unroll
        for (int s = 0; s < 4; ++s)
            acc = __builtin_amdgcn_mfma_f32_16x16x32_bf16(afrag[s], bfrag[s], acc, 0, 0, 0);

        float bcol = biasTab[l16];
#pragma unroll
        for (int r = 0; r < 4; ++r) {
            float lg = acc[r] + bcol;                 // -3e38 for pad cols
            float mx = lg;
            mx = fmaxf(mx, __shfl_xor(mx, 1));
            mx = fmaxf(mx, __shfl_xor(mx, 2));
            mx = fmaxf(mx, __shfl_xor(mx, 4));
            mx = fmaxf(mx, __shfl_xor(mx, 8));
            float p = __expf(lg - mx);                // pad cols -> 0
            float se = p;
            se += __shfl_xor(se, 1);
            se += __shfl_xor(se, 2);
            se += __shfl_xor(se, 4);
            se += __shfl_xor(se, 8);
            float ls = __logf(se);
            int grow = r0 + wv * 16 + half * 4 + r;
            if (l16 < N_CLASS && grow < N)
                out[grow * N_CLASS + l16] = lg - mx - ls;
        }
    }
}

// ===========================================================================

extern "C" void kernel_launch(void* const* d_in, const int* in_sizes, int n_in,
                              void* d_out, int out_size, void* d_ws, size_t ws_size,
                              hipStream_t stream) {
    const float* x   = (const float*)d_in[0];
    const float* w11 = (const float*)d_in[2];
    const float* b11 = (const float*)d_in[3];
    const float* g11 = (const float*)d_in[4];
    const float* t11 = (const float*)d_in[5];
    const float* w12 = (const float*)d_in[6];
    const float* b12 = (const float*)d_in[7];
    const float* g12 = (const float*)d_in[8];
    const float* t12 = (const float*)d_in[9];
    const float* w21 = (const float*)d_in[10];
    const float* b21 = (const float*)d_in[11];
    const float* g21 = (const float*)d_in[12];
    const float* t21 = (const float*)d_in[13];
    const float* w22 = (const float*)d_in[14];
    const float* b22 = (const float*)d_in[15];
    const float* g22 = (const float*)d_in[16];
    const float* t22 = (const float*)d_in[17];
    const float* wf  = (const float*)d_in[18];
    const float* bf  = (const float*)d_in[19];
    const int*   ei  = (const int*)d_in[20];

    const int N = in_sizes[0] / N_CLASS;      // 100000
    const int E = in_sizes[1];                // 1600000
    const float inv_n = 1.0f / (float)N;
    const int NBK = (N + 255) >> 8;           // 391 buckets (<= 512)

    // ---- workspace layout: EVERY section 256B-aligned (row = 4 cache lines;
    //      16B-align left bufA/B/C at 32 mod 256 -> 5-line rows, +25% FETCH) --
    char* base = (char*)d_ws;
    size_t off = 0;
    auto take = [&](size_t bytes) { void* p = base + off; off += (bytes + 255) & ~(size_t)255; return p; };
    float*          stats   = (float*)take(1024 * 4);
    unsigned short* xp      = (unsigned short*)take((size_t)N * 16 * 2);
    float*          h0      = (float*)take((size_t)N * 16 * 4);
    int*            cnt     = (int*)take((size_t)N * 4);
    int*            row_ptr = (int*)take((size_t)N * 4);
    int*            bhist   = (int*)take(512 * 4);
    int*            bstart  = (int*)take(520 * 4);
    int*            bbase   = (int*)take(512 * 256 * 4);   // [bucket][block]
    unsigned int*   pairs   = (unsigned int*)take((size_t)E * 4);
    int*            col     = (int*)take((size_t)E * 4);
    unsigned short* bufA    = (unsigned short*)take((size_t)N * HIDDEN * 2);
    unsigned short* bufB    = (unsigned short*)take((size_t)N * HIDDEN * 2);
    unsigned short* bufC    = (unsigned short*)take((size_t)N * HIDDEN * 2);
    unsigned short* Wt1     = (unsigned short*)take(128 * 128 * 2);
    unsigned short* Wt2     = (unsigned short*)take(128 * 128 * 2);
    unsigned short* Wt3     = (unsigned short*)take(128 * 128 * 2);

    // ---- prep: weights->bf16^T + zero stats/bhist; padx at full grid ----
    prep_k<<<dim3(64, 3), 256, 0, stream>>>(w12, w21, w22, Wt1, Wt2, Wt3,
                                            stats, bhist);
    padx_k<<<(N * 16 + 255) / 256, 256, 0, stream>>>(x, xp, N);

    // ---- bucketed CSR build (atomic-free scatter via per-block histograms) --
    bhist_k<<<256, 512, 0, stream>>>(ei, bhist, bbase, E);
    bscan_k<<<1, 512, 0, stream>>>(bhist, bstart, NBK);
    bscan2_k<<<NBK, 256, 0, stream>>>(bbase, bstart);
    bscatter_k<<<256, 512, 0, stream>>>(ei, bbase, pairs, E);
    bcsr_k<<<NBK, 512, 0, stream>>>(pairs, bstart, row_ptr, cnt, col, N);

    // ---- layer 1 ----
    gather10_k<<<(N * 16 + 255) / 256, 256, 0, stream>>>(xp, col, row_ptr, cnt, h0, N);
    gemm10_k<<<512, 128, 0, stream>>>(h0, w11, b11, bufA, stats, N);            // Z1 + stats0
    gemm_mfma_k<true><<<768, 256, 0, stream>>>(bufA, Wt1, b12, stats, g11, t11,
                                               bufB, stats + 256, N, inv_n);    // Z2 + stats1

    // ---- layer 2 aggregation: activate once per node, then pure-sum gather --
    act2_k<<<3125, 256, 0, stream>>>(bufB, bufC, stats + 256, g12, t12, N, inv_n);
    gather_sum_k<<<(N * 64 + 255) / 256, 256, 0, stream>>>(bufC, col, row_ptr, cnt,
                                                           bufA, N);

    // ---- layer 2 MLP ----
    gemm_mfma_k<false><<<768, 256, 0, stream>>>(bufA, Wt2, b21, nullptr, nullptr, nullptr,
                                                bufB, stats + 512, N, inv_n);   // Z3 + stats2
    gemm_mfma_k<true><<<768, 256, 0, stream>>>(bufB, Wt3, b22, stats + 512, g21, t21,
                                               bufA, stats + 768, N, inv_n);    // Z4 + stats3

    // ---- final linear + log_softmax (BN4+ReLU fused, MFMA) ----
    final_mfma_k<<<782, 256, 0, stream>>>(bufA, stats + 768, g22, t22,
                                          wf, bf, (float*)d_out, N, inv_n);
}